// Round 6
// baseline (494.579 us; speedup 1.0000x reference)
//
#include <hip/hip_runtime.h>
#include <stdint.h>

// NeighborAttention, MI355X gfx950 — round 6: barrier-free wave-per-node hot
// kernel. B=4,N=4096,K=32,C=128,H=4,d=32.
//  A: T = (X·WQ^T)·WK per head, scaled -> ws (bf16). (r5 verbatim)
//  B2: one wave per node, NO LDS, NO barriers. E frags global->reg (serve as
//      scores B-operand AND PV A-operand). scores = mfma(A=t, B=E) -> quad0
//      lanes hold attn[h][k]; shfl softmax in lanes 0-15; attn redistributed
//      by __shfl; PV = mfma(A=E, B=WV) + shuffle aggregation; cat -> ws.
//      16384 independent waves, ~12/CU resident: latency hidden by TLP like
//      the 6.7TB/s fill kernel (10% occupancy, no dependencies).
//  C: out = cat·WO^T (r5 verbatim).
// dtype (fp32 vs bf16) detected in-kernel. Numerics: same rounding points as
// r4/r5 (E,t,cat bf16; scores/softmax/aggregation fp32).

typedef __attribute__((ext_vector_type(8))) short short8;   // 8 bf16 = 16 B
typedef __attribute__((ext_vector_type(4))) float f32x4;

#define CDIM  128
#define KN    32
#define ESTR  136   // padded LDS row stride (bf16 units) for kernel A
#define NEGI  -3.0e38f

__device__ __forceinline__ float bf2f(short s) {
    union { unsigned int u; float f; } v;
    v.u = ((unsigned int)(unsigned short)s) << 16;
    return v.f;
}
__device__ __forceinline__ short f2bf(float f) {
    union { float ff; unsigned int u; } v; v.ff = f;
    unsigned int u = v.u;
    u += 0x7FFFu + ((u >> 16) & 1u);   // round-to-nearest-even
    return (short)(u >> 16);
}

template<bool FP32>
__device__ __forceinline__ short8 load8bf(const void* p, size_t idx) {
    if constexpr (FP32) {
        const float* fp = (const float*)p + idx;
        f32x4 a = *(const f32x4*)fp;
        f32x4 b = *(const f32x4*)(fp + 4);
        short8 r;
        r[0] = f2bf(a[0]); r[1] = f2bf(a[1]); r[2] = f2bf(a[2]); r[3] = f2bf(a[3]);
        r[4] = f2bf(b[0]); r[5] = f2bf(b[1]); r[6] = f2bf(b[2]); r[7] = f2bf(b[3]);
        return r;
    } else {
        return *(const short8*)((const short*)p + idx);
    }
}

template<bool FP32>
__device__ __forceinline__ short loadbf1(const void* p, size_t idx) {
    if constexpr (FP32) return f2bf(((const float*)p)[idx]);
    else return ((const short*)p)[idx];
}

// in-kernel dtype detect: fp32 low half-words decode to wild/NaN bf16s
__device__ __forceinline__ bool detect_fp32(const short* wp) {
    const int lane = threadIdx.x & 63;
    int cnt = 0;
    #pragma unroll
    for (int i = 0; i < 8; ++i) {
        const float v = bf2f(wp[lane + i * 64]);
        if (!(fabsf(v) < 8.0f)) cnt++;
    }
    #pragma unroll
    for (int d = 1; d < 64; d <<= 1) cnt += __shfl_xor(cnt, d);
    return cnt > 16;
}

// ===================== kernel A: T precompute (r5 verbatim) =====================
#define ANPB 64
struct alignas(16) SmemA {
    short sX[ANPB * ESTR];   // 17408 B
    short sQ[ANPB * ESTR];   // 17408 B
};                           // 34816 B

template<bool FP32>
__device__ __forceinline__ void naA_body(SmemA& sm, const void* __restrict__ hX,
    const void* __restrict__ WQ, const void* __restrict__ WK, short* __restrict__ Tg)
{
    const int tid = threadIdx.x, lane = tid & 63, w = tid >> 6;
    const int quad = lane >> 4, l15 = lane & 15;
    const int nbA = blockIdx.x * ANPB;

    #pragma unroll
    for (int it = 0; it < 4; ++it) {
        const int chunk = it * 256 + tid, row = chunk >> 4, cc = chunk & 15;
        *(short8*)&sm.sX[row * ESTR + cc * 8] =
            load8bf<FP32>(hX, (size_t)nbA * CDIM + (size_t)chunk * 8);
    }
    short8 bq[2][4];
    #pragma unroll
    for (int t2 = 0; t2 < 2; ++t2)
        #pragma unroll
        for (int kk = 0; kk < 4; ++kk)
            bq[t2][kk] = load8bf<FP32>(WQ, (size_t)(w * 32 + t2 * 16 + l15) * CDIM + kk * 32 + quad * 8);
    __syncthreads();

    #pragma unroll
    for (int mt = 0; mt < 4; ++mt) {
        short8 ax[4];
        #pragma unroll
        for (int kk = 0; kk < 4; ++kk)
            ax[kk] = *(const short8*)&sm.sX[(mt * 16 + l15) * ESTR + kk * 32 + quad * 8];
        f32x4 o0 = {0.f,0.f,0.f,0.f}, o1 = {0.f,0.f,0.f,0.f};
        #pragma unroll
        for (int kk = 0; kk < 4; ++kk) {
            o0 = __builtin_amdgcn_mfma_f32_16x16x32_bf16(ax[kk], bq[0][kk], o0, 0, 0, 0);
            o1 = __builtin_amdgcn_mfma_f32_16x16x32_bf16(ax[kk], bq[1][kk], o1, 0, 0, 0);
        }
        #pragma unroll
        for (int r = 0; r < 4; ++r) {
            const int row = mt * 16 + quad * 4 + r;
            sm.sQ[row * ESTR + w * 32 + l15]      = f2bf(o0[r]);
            sm.sQ[row * ESTR + w * 32 + 16 + l15] = f2bf(o1[r]);
        }
    }
    __syncthreads();

    short8 bk[2][4];
    #pragma unroll
    for (int t2 = 0; t2 < 2; ++t2)
        #pragma unroll
        for (int kk = 0; kk < 4; ++kk) {
            const int j = w * 32 + t2 * 16 + l15;
            short8 b;
            #pragma unroll
            for (int jj = 0; jj < 8; ++jj)
                b[jj] = loadbf1<FP32>(WK, (size_t)(kk * 32 + quad * 8 + jj) * CDIM + j);
            bk[t2][kk] = b;
        }

    const float scale = 0.17677669529663687f;   // 1/sqrt(32)
    const short8 zz = {0,0,0,0,0,0,0,0};
    #pragma unroll
    for (int m = 0; m < 16; ++m) {
        const int n_g = (m * 16 + l15) >> 2, h_ = l15 & 3;
        const short8 qv = *(const short8*)&sm.sQ[n_g * ESTR + h_ * 32 + quad * 8];
        f32x4 c0 = {0.f,0.f,0.f,0.f}, c1 = {0.f,0.f,0.f,0.f};
        #pragma unroll
        for (int kk = 0; kk < 4; ++kk) {
            const short8 af = (kk == h_) ? qv : zz;
            c0 = __builtin_amdgcn_mfma_f32_16x16x32_bf16(af, bk[0][kk], c0, 0, 0, 0);
            c1 = __builtin_amdgcn_mfma_f32_16x16x32_bf16(af, bk[1][kk], c1, 0, 0, 0);
        }
        #pragma unroll
        for (int r = 0; r < 4; ++r) {
            const int rg = m * 16 + quad * 4 + r;
            const size_t base = (size_t)(nbA + (rg >> 2)) * 512 + (rg & 3) * 128 + w * 32;
            Tg[base + l15]      = f2bf(c0[r] * scale);
            Tg[base + 16 + l15] = f2bf(c1[r] * scale);
        }
    }
}

__global__ __launch_bounds__(256, 3)
void naA(const void* __restrict__ hX, const void* __restrict__ WQ,
         const void* __restrict__ WK, short* __restrict__ Tg)
{
    __shared__ SmemA sm;
    if (detect_fp32((const short*)WQ)) naA_body<true >(sm, hX, WQ, WK, Tg);
    else                               naA_body<false>(sm, hX, WQ, WK, Tg);
}

// ===================== kernel B2: wave-per-node, barrier/LDS-free ============
template<bool FP32>
__device__ __forceinline__ void naB2_node(int node, const void* __restrict__ hE,
    const int* __restrict__ mask, const void* __restrict__ WV,
    const short* __restrict__ Tg, short* __restrict__ catG)
{
    const int lane = threadIdx.x & 63;
    const int quad = lane >> 4, l15 = lane & 15;
    const size_t eb = (size_t)node * (KN * CDIM);

    // E fragments, global -> reg, exactly once per node.
    // Lane l15 = row k (tile0: k=l15, tile1: k=16+l15); elems kk*32+quad*8..
    // Per (kk,tile) instruction the wave covers 16 rows x 128 B — 64-B coalesced.
    short8 aE0[4], aE1[4];
    #pragma unroll
    for (int kk = 0; kk < 4; ++kk) {
        aE0[kk] = load8bf<FP32>(hE, eb + (size_t)l15 * CDIM + kk * 32 + quad * 8);
        aE1[kk] = load8bf<FP32>(hE, eb + (size_t)(16 + l15) * CDIM + kk * 32 + quad * 8);
    }

    // t fragments: A-operand rows = head h. Clamp row index so lanes 4-15
    // duplicate valid heads (never OOB, never NaN).
    short8 tq[4];
    #pragma unroll
    for (int kk = 0; kk < 4; ++kk)
        tq[kk] = *(const short8*)(Tg + (size_t)node * 512 + (l15 & 3) * 128 + kk * 32 + quad * 8);

    // mask for this lane's two k's (only lanes 0-15 matter)
    const int mk0 = mask[(size_t)node * KN + l15];
    const int mk1 = mask[(size_t)node * KN + 16 + l15];

    // scores = t · E^T : C[h][k], rows=h (quad0 regs), cols=k (l15)
    f32x4 s0 = {0.f,0.f,0.f,0.f}, s1 = {0.f,0.f,0.f,0.f};
    #pragma unroll
    for (int kk = 0; kk < 4; ++kk) {
        s0 = __builtin_amdgcn_mfma_f32_16x16x32_bf16(tq[kk], aE0[kk], s0, 0, 0, 0);
        s1 = __builtin_amdgcn_mfma_f32_16x16x32_bf16(tq[kk], aE1[kk], s1, 0, 0, 0);
    }

    // masked softmax over k, per head r (valid in lanes 0-15; shfl_xor 1,2,4,8
    // stays inside lanes 0-15)
    float x0[4], x1[4], ainv[4];
    {
        float m[4], ds[4];
        #pragma unroll
        for (int r = 0; r < 4; ++r) {
            const float a = (mk0 > 0) ? s0[r] : NEGI;
            const float b = (mk1 > 0) ? s1[r] : NEGI;
            m[r] = fmaxf(a, b);
        }
        #pragma unroll
        for (int d = 1; d < 16; d <<= 1)
            #pragma unroll
            for (int r = 0; r < 4; ++r) m[r] = fmaxf(m[r], __shfl_xor(m[r], d));
        #pragma unroll
        for (int r = 0; r < 4; ++r) {
            x0[r] = __expf(fminf(s0[r] - m[r], 0.f)) * ((mk0 > 0) ? 1.f : 0.f);
            x1[r] = __expf(fminf(s1[r] - m[r], 0.f)) * ((mk1 > 0) ? 1.f : 0.f);
            ds[r] = x0[r] + x1[r];
        }
        #pragma unroll
        for (int d = 1; d < 16; d <<= 1)
            #pragma unroll
            for (int r = 0; r < 4; ++r) ds[r] += __shfl_xor(ds[r], d);
        #pragma unroll
        for (int r = 0; r < 4; ++r) {
            const float inv = (ds[r] > 0.f) ? (1.f / ds[r]) : 0.f;
            x0[r] *= inv; x1[r] *= inv;
            ainv[r] = 1.0f / (((ds[r] > 0.f) ? 1.0f : 0.0f) + 1e-8f);
        }
    }

    // PV + aggregation: per col-tile ct (cols c = ct*16+l15, head h = ct>>1).
    // attn[h][k=quad*4+r] pulled from quad0 lane (quad*4+r) via __shfl;
    // h is compile-time (full unroll) so x0[h]/x1[h] are static reg indices.
    const size_t ng = (size_t)node * 384;
    #pragma unroll
    for (int ct = 0; ct < 8; ++ct) {
        const int h = ct >> 1;
        float aA[4], aB[4];
        #pragma unroll
        for (int r = 0; r < 4; ++r) {
            aA[r] = __shfl(x0[h], quad * 4 + r);
            aB[r] = __shfl(x1[h], quad * 4 + r);
        }
        f32x4 av0 = {0.f,0.f,0.f,0.f}, av1 = {0.f,0.f,0.f,0.f};
        #pragma unroll
        for (int kk = 0; kk < 4; ++kk) {
            const short8 bvf = load8bf<FP32>(WV, (size_t)(ct * 16 + l15) * CDIM + kk * 32 + quad * 8);
            av0 = __builtin_amdgcn_mfma_f32_16x16x32_bf16(aE0[kk], bvf, av0, 0, 0, 0);
            av1 = __builtin_amdgcn_mfma_f32_16x16x32_bf16(aE1[kk], bvf, av1, 0, 0, 0);
        }
        float sum = 0.f, mx = NEGI;
        #pragma unroll
        for (int r = 0; r < 4; ++r) {
            const float p0 = aA[r] * av0[r];
            const float p1 = aB[r] * av1[r];
            sum += p0 + p1;
            mx = fmaxf(mx, fmaxf(p0, p1));
        }
        sum += __shfl_xor(sum, 16);
        sum += __shfl_xor(sum, 32);
        mx = fmaxf(mx, __shfl_xor(mx, 16));
        mx = fmaxf(mx, __shfl_xor(mx, 32));
        if (quad == 0) {
            const int c = ct * 16 + l15;
            catG[ng + c]       = f2bf(sum * ainv[h]);  // mean
            catG[ng + 128 + c] = f2bf(sum);            // sum
            catG[ng + 256 + c] = f2bf(mx);             // max
        }
    }
}

__global__ __launch_bounds__(256, 3)
void naB2(const void* __restrict__ hE, const int* __restrict__ mask,
          const void* __restrict__ WV, const short* __restrict__ Tg,
          short* __restrict__ catG)
{
    const int node = blockIdx.x * 4 + (threadIdx.x >> 6);   // wave-per-node
    if (detect_fp32((const short*)WV)) naB2_node<true >(node, hE, mask, WV, Tg, catG);
    else                               naB2_node<false>(node, hE, mask, WV, Tg, catG);
}

// ===================== kernel C: out = cat @ WO^T (r5 verbatim) ==============
struct alignas(16) SmemC {
    short sCat[16 * 392];   // 12544 B
};

template<bool FP32>
__device__ __forceinline__ void naC_body(SmemC& sm, const short* __restrict__ catG,
    const void* __restrict__ WO, void* __restrict__ out)
{
    const int tid = threadIdx.x, lane = tid & 63, w = tid >> 6;
    const int quad = lane >> 4, l15 = lane & 15;
    const int nb = blockIdx.x * 16;

    #pragma unroll
    for (int it = 0; it < 3; ++it) {
        const int chunk = it * 256 + tid;
        const int row = chunk / 48, cc = chunk % 48;
        *(short8*)&sm.sCat[row * 392 + cc * 8] =
            *(const short8*)&catG[(size_t)nb * 384 + (size_t)chunk * 8];
    }
    __syncthreads();

    f32x4 o0 = {0.f,0.f,0.f,0.f}, o1 = {0.f,0.f,0.f,0.f};
    #pragma unroll
    for (int kk = 0; kk < 12; ++kk) {
        const short8 a  = *(const short8*)&sm.sCat[l15 * 392 + kk * 32 + quad * 8];
        const short8 b0 = load8bf<FP32>(WO, (size_t)(w * 32 + l15) * 384 + kk * 32 + quad * 8);
        const short8 b1 = load8bf<FP32>(WO, (size_t)(w * 32 + 16 + l15) * 384 + kk * 32 + quad * 8);
        o0 = __builtin_amdgcn_mfma_f32_16x16x32_bf16(a, b0, o0, 0, 0, 0);
        o1 = __builtin_amdgcn_mfma_f32_16x16x32_bf16(a, b1, o1, 0, 0, 0);
    }
    #pragma unroll
    for (int r = 0; r < 4; ++r) {
        const int node = quad * 4 + r;
        const size_t base = (size_t)(nb + node) * CDIM + w * 32;
        if constexpr (FP32) {
            ((float*)out)[base + l15]      = o0[r];
            ((float*)out)[base + 16 + l15] = o1[r];
        } else {
            ((short*)out)[base + l15]      = f2bf(o0[r]);
            ((short*)out)[base + 16 + l15] = f2bf(o1[r]);
        }
    }
}

__global__ __launch_bounds__(256, 4)
void naC(const short* __restrict__ catG, const void* __restrict__ WO,
         void* __restrict__ out)
{
    __shared__ SmemC sm;
    if (detect_fp32((const short*)WO)) naC_body<true >(sm, catG, WO, out);
    else                               naC_body<false>(sm, catG, WO, out);
}

extern "C" void kernel_launch(void* const* d_in, const int* in_sizes, int n_in,
                              void* d_out, int out_size, void* d_ws, size_t ws_size,
                              hipStream_t stream) {
    (void)in_sizes; (void)n_in; (void)ws_size; (void)out_size;
    const void* hX   = d_in[0];
    const void* hE   = d_in[1];
    const int*  mask = (const int*)d_in[2];
    const void* WQ   = d_in[3];
    const void* WK   = d_in[4];
    const void* WV   = d_in[5];
    const void* WO   = d_in[6];

    short* Tg   = (short*)d_ws;                             // 16384*512*2 = 16.8 MB
    short* catG = (short*)((char*)d_ws + (32u << 20));      // 16384*384*2 = 12.6 MB

    naA <<<dim3(256),  dim3(256), 0, stream>>>(hX, WQ, WK, Tg);
    naB2<<<dim3(4096), dim3(256), 0, stream>>>(hE, mask, WV, Tg, catG);
    naC <<<dim3(1024), dim3(256), 0, stream>>>(catG, WO, d_out);
}

// Round 7
// 433.310 us; speedup vs baseline: 1.1414x; 1.1414x over previous
//
#include <hip/hip_runtime.h>
#include <stdint.h>

// NeighborAttention, MI355X gfx950 — round 7: request-amortization round.
// B=4,N=4096,K=32,C=128,H=4,d=32.
// Model (r6 post-mortem): the chip is L2 line-REQUEST-rate bound, not byte
// bound. Fix = amortize weight re-reads per block.
//  A: T = (X·WQ^T)·WK scaled -> ws (r5 verbatim, 64 nodes/block).
//  B: r5 E-streamer, NPB 16->32 (grid 512): WV frags + T prefetch + prologue
//     amortized 2x. Same LDS layout (+2KB mask) -> still 3 blocks/CU.
//  C: out = cat·WO^T, 64 nodes/block (grid 256): WO frags loaded once/wave,
//     reused across 4 M-tiles (requests /4). cat staged to 50KB LDS.
// dtype (fp32 vs bf16) detected in-kernel. Numerics identical to r4/r5/r6.

typedef __attribute__((ext_vector_type(8))) short short8;   // 8 bf16 = 16 B
typedef __attribute__((ext_vector_type(4))) float f32x4;

#define CDIM  128
#define KN    32
#define ESTR  136   // padded LDS row stride (bf16 units)
#define SSTR  36    // attn row stride (fp32), 32 attn + [33]=ainv
#define NEGI  -3.0e38f

__device__ __forceinline__ float bf2f(short s) {
    union { unsigned int u; float f; } v;
    v.u = ((unsigned int)(unsigned short)s) << 16;
    return v.f;
}
__device__ __forceinline__ short f2bf(float f) {
    union { float ff; unsigned int u; } v; v.ff = f;
    unsigned int u = v.u;
    u += 0x7FFFu + ((u >> 16) & 1u);   // round-to-nearest-even
    return (short)(u >> 16);
}

template<bool FP32>
__device__ __forceinline__ short8 load8bf(const void* p, size_t idx) {
    if constexpr (FP32) {
        const float* fp = (const float*)p + idx;
        f32x4 a = *(const f32x4*)fp;
        f32x4 b = *(const f32x4*)(fp + 4);
        short8 r;
        r[0] = f2bf(a[0]); r[1] = f2bf(a[1]); r[2] = f2bf(a[2]); r[3] = f2bf(a[3]);
        r[4] = f2bf(b[0]); r[5] = f2bf(b[1]); r[6] = f2bf(b[2]); r[7] = f2bf(b[3]);
        return r;
    } else {
        return *(const short8*)((const short*)p + idx);
    }
}

template<bool FP32>
__device__ __forceinline__ short loadbf1(const void* p, size_t idx) {
    if constexpr (FP32) return f2bf(((const float*)p)[idx]);
    else return ((const short*)p)[idx];
}

// in-kernel dtype detect: fp32 low half-words decode to wild/NaN bf16s
__device__ __forceinline__ bool detect_fp32(const short* wp) {
    const int lane = threadIdx.x & 63;
    int cnt = 0;
    #pragma unroll
    for (int i = 0; i < 8; ++i) {
        const float v = bf2f(wp[lane + i * 64]);
        if (!(fabsf(v) < 8.0f)) cnt++;
    }
    #pragma unroll
    for (int d = 1; d < 64; d <<= 1) cnt += __shfl_xor(cnt, d);
    return cnt > 16;
}

// ===================== kernel A: T precompute (r5 verbatim) ==================
#define ANPB 64
struct alignas(16) SmemA {
    short sX[ANPB * ESTR];   // 17408 B
    short sQ[ANPB * ESTR];   // 17408 B
};                           // 34816 B

template<bool FP32>
__device__ __forceinline__ void naA_body(SmemA& sm, const void* __restrict__ hX,
    const void* __restrict__ WQ, const void* __restrict__ WK, short* __restrict__ Tg)
{
    const int tid = threadIdx.x, lane = tid & 63, w = tid >> 6;
    const int quad = lane >> 4, l15 = lane & 15;
    const int nbA = blockIdx.x * ANPB;

    #pragma unroll
    for (int it = 0; it < 4; ++it) {
        const int chunk = it * 256 + tid, row = chunk >> 4, cc = chunk & 15;
        *(short8*)&sm.sX[row * ESTR + cc * 8] =
            load8bf<FP32>(hX, (size_t)nbA * CDIM + (size_t)chunk * 8);
    }
    short8 bq[2][4];
    #pragma unroll
    for (int t2 = 0; t2 < 2; ++t2)
        #pragma unroll
        for (int kk = 0; kk < 4; ++kk)
            bq[t2][kk] = load8bf<FP32>(WQ, (size_t)(w * 32 + t2 * 16 + l15) * CDIM + kk * 32 + quad * 8);
    __syncthreads();

    #pragma unroll
    for (int mt = 0; mt < 4; ++mt) {
        short8 ax[4];
        #pragma unroll
        for (int kk = 0; kk < 4; ++kk)
            ax[kk] = *(const short8*)&sm.sX[(mt * 16 + l15) * ESTR + kk * 32 + quad * 8];
        f32x4 o0 = {0.f,0.f,0.f,0.f}, o1 = {0.f,0.f,0.f,0.f};
        #pragma unroll
        for (int kk = 0; kk < 4; ++kk) {
            o0 = __builtin_amdgcn_mfma_f32_16x16x32_bf16(ax[kk], bq[0][kk], o0, 0, 0, 0);
            o1 = __builtin_amdgcn_mfma_f32_16x16x32_bf16(ax[kk], bq[1][kk], o1, 0, 0, 0);
        }
        #pragma unroll
        for (int r = 0; r < 4; ++r) {
            const int row = mt * 16 + quad * 4 + r;
            sm.sQ[row * ESTR + w * 32 + l15]      = f2bf(o0[r]);
            sm.sQ[row * ESTR + w * 32 + 16 + l15] = f2bf(o1[r]);
        }
    }
    __syncthreads();

    short8 bk[2][4];
    #pragma unroll
    for (int t2 = 0; t2 < 2; ++t2)
        #pragma unroll
        for (int kk = 0; kk < 4; ++kk) {
            const int j = w * 32 + t2 * 16 + l15;
            short8 b;
            #pragma unroll
            for (int jj = 0; jj < 8; ++jj)
                b[jj] = loadbf1<FP32>(WK, (size_t)(kk * 32 + quad * 8 + jj) * CDIM + j);
            bk[t2][kk] = b;
        }

    const float scale = 0.17677669529663687f;   // 1/sqrt(32)
    const short8 zz = {0,0,0,0,0,0,0,0};
    #pragma unroll
    for (int m = 0; m < 16; ++m) {
        const int n_g = (m * 16 + l15) >> 2, h_ = l15 & 3;
        const short8 qv = *(const short8*)&sm.sQ[n_g * ESTR + h_ * 32 + quad * 8];
        f32x4 c0 = {0.f,0.f,0.f,0.f}, c1 = {0.f,0.f,0.f,0.f};
        #pragma unroll
        for (int kk = 0; kk < 4; ++kk) {
            const short8 af = (kk == h_) ? qv : zz;
            c0 = __builtin_amdgcn_mfma_f32_16x16x32_bf16(af, bk[0][kk], c0, 0, 0, 0);
            c1 = __builtin_amdgcn_mfma_f32_16x16x32_bf16(af, bk[1][kk], c1, 0, 0, 0);
        }
        #pragma unroll
        for (int r = 0; r < 4; ++r) {
            const int rg = m * 16 + quad * 4 + r;
            const size_t base = (size_t)(nbA + (rg >> 2)) * 512 + (rg & 3) * 128 + w * 32;
            Tg[base + l15]      = f2bf(c0[r] * scale);
            Tg[base + 16 + l15] = f2bf(c1[r] * scale);
        }
    }
}

__global__ __launch_bounds__(256, 3)
void naA(const void* __restrict__ hX, const void* __restrict__ WQ,
         const void* __restrict__ WK, short* __restrict__ Tg)
{
    __shared__ SmemA sm;
    if (detect_fp32((const short*)WQ)) naA_body<true >(sm, hX, WQ, WK, Tg);
    else                               naA_body<false>(sm, hX, WQ, WK, Tg);
}

// ===================== kernel B: E streamer, NPB=32 ==========================
#define NPB 32
#define NST (NPB / 4)   // 8 subtiles of 128 rows
struct alignas(16) SmemB {
    short sE[128 * ESTR];      // 34816 B  E subtile (bf16)
    short sTb[2][16 * ESTR];   //  8704 B  T double buffer
    float sS[16 * SSTR];       //  2304 B  attn rows (+[33]=ainv), per subtile
    int   sMask[NPB * KN];     //  4096 B
};                             // 49920 B -> 3 blocks/CU

template<bool FP32>
__device__ __forceinline__ void issueE(const void* hE, size_t base, int tid,
                                       f32x4 (&eF)[8][2], short8 (&eB)[8]) {
    if constexpr (FP32) {
        #pragma unroll
        for (int it = 0; it < 8; ++it) {
            const float* p = (const float*)hE + base + (size_t)(it * 256 + tid) * 8;
            eF[it][0] = *(const f32x4*)p;
            eF[it][1] = *(const f32x4*)(p + 4);
        }
    } else {
        #pragma unroll
        for (int it = 0; it < 8; ++it)
            eB[it] = *(const short8*)((const short*)hE + base + (size_t)(it * 256 + tid) * 8);
    }
}

template<bool FP32>
__device__ __forceinline__ void writeE(short* sE, int tid,
                                       const f32x4 (&eF)[8][2], const short8 (&eB)[8]) {
    #pragma unroll
    for (int it = 0; it < 8; ++it) {
        const int chunk = it * 256 + tid, row = chunk >> 4, cc = chunk & 15;
        short8 v;
        if constexpr (FP32) {
            #pragma unroll
            for (int t = 0; t < 4; ++t) { v[t] = f2bf(eF[it][0][t]); v[4 + t] = f2bf(eF[it][1][t]); }
        } else v = eB[it];
        *(short8*)&sE[row * ESTR + cc * 8] = v;
    }
}

template<bool FP32>
__device__ __forceinline__ void naB_body(SmemB& sm, const void* __restrict__ hE,
    const int* __restrict__ mask, const void* __restrict__ WV,
    const short* __restrict__ Tg, short* __restrict__ catG)
{
    const int tid = threadIdx.x, lane = tid & 63, w = tid >> 6;
    const int quad = lane >> 4, l15 = lane & 15;
    const int nb = blockIdx.x * NPB;
    const size_t ebase = (size_t)nb * (KN * CDIM);

    f32x4 eF[8][2]; short8 eB[8]; short8 eT;
    issueE<FP32>(hE, ebase, tid, eF, eB);
    eT = *(const short8*)(Tg + (size_t)nb * 512 + tid * 8);
    __builtin_amdgcn_sched_barrier(0);   // pin: do not sink prefetch

    // mask stage (coalesced, 4 ints/thread)
    *(int4*)&sm.sMask[tid * 4] = *(const int4*)&mask[(size_t)nb * KN + tid * 4];

    // WV B-frags, block lifetime (wave w owns channel cols 32w..32w+31)
    short8 bv[2][4];
    #pragma unroll
    for (int ct2 = 0; ct2 < 2; ++ct2)
        #pragma unroll
        for (int kk = 0; kk < 4; ++kk)
            bv[ct2][kk] = load8bf<FP32>(WV, (size_t)((2 * w + ct2) * 16 + l15) * CDIM + kk * 32 + quad * 8);

    // stage subtile 0, issue subtile 1
    writeE<FP32>(sm.sE, tid, eF, eB);
    { const int row = tid >> 4, cc = tid & 15;
      *(short8*)&sm.sTb[0][row * ESTR + cc * 8] = eT; }
    issueE<FP32>(hE, ebase + 128 * 128, tid, eF, eB);
    eT = *(const short8*)(Tg + (size_t)(nb + 4) * 512 + tid * 8);
    __builtin_amdgcn_sched_barrier(0);
    __syncthreads();   // B0: sE=E0, sTb0=T0, sMask ready

    #pragma unroll 1
    for (int s = 0; s < NST; ++s) {
        const short* tb = sm.sTb[s & 1];

        // P4: scores = E·T^T for own node (cols l15=(n,h); all computed, n==w kept)
        short8 bs[4], a0[4], a1[4];
        #pragma unroll
        for (int kk = 0; kk < 4; ++kk) {
            bs[kk] = *(const short8*)&tb[l15 * ESTR + kk * 32 + quad * 8];
            a0[kk] = *(const short8*)&sm.sE[(w * 32 + l15) * ESTR + kk * 32 + quad * 8];
            a1[kk] = *(const short8*)&sm.sE[(w * 32 + 16 + l15) * ESTR + kk * 32 + quad * 8];
        }
        f32x4 s0 = {0.f,0.f,0.f,0.f}, s1 = {0.f,0.f,0.f,0.f};
        #pragma unroll
        for (int kk = 0; kk < 4; ++kk) {
            s0 = __builtin_amdgcn_mfma_f32_16x16x32_bf16(a0[kk], bs[kk], s0, 0, 0, 0);
            s1 = __builtin_amdgcn_mfma_f32_16x16x32_bf16(a1[kk], bs[kk], s1, 0, 0, 0);
        }

        // in-register masked softmax (per column (n,h)=l15, k across quads)
        {
            const int* mp = &sm.sMask[(s * 4 + (l15 >> 2)) * KN];
            float x[8]; int mk[8];
            #pragma unroll
            for (int j = 0; j < 4; ++j) {
                x[j] = s0[j];     mk[j]     = mp[quad * 4 + j];
                x[4 + j] = s1[j]; mk[4 + j] = mp[16 + quad * 4 + j];
            }
            float m = NEGI;
            #pragma unroll
            for (int j = 0; j < 8; ++j) m = fmaxf(m, (mk[j] > 0) ? x[j] : NEGI);
            m = fmaxf(m, __shfl_xor(m, 16));
            m = fmaxf(m, __shfl_xor(m, 32));
            float dsum = 0.f;
            #pragma unroll
            for (int j = 0; j < 8; ++j) {
                const float e = __expf(fminf(x[j] - m, 0.f)) * ((mk[j] > 0) ? 1.f : 0.f);
                x[j] = e; dsum += e;
            }
            dsum += __shfl_xor(dsum, 16);
            dsum += __shfl_xor(dsum, 32);
            const float inv = (dsum > 0.f) ? (1.f / dsum) : 0.f;
            if ((l15 >> 2) == w) {              // owner lanes publish attn
                float* sp = &sm.sS[(w * 4 + (l15 & 3)) * SSTR];
                #pragma unroll
                for (int j = 0; j < 4; ++j) {
                    sp[quad * 4 + j]      = x[j] * inv;
                    sp[16 + quad * 4 + j] = x[4 + j] * inv;
                }
                if (quad == 0)
                    sp[33] = 1.0f / (((dsum > 0.f) ? 1.0f : 0.0f) + 1e-8f);
            }
        }
        __syncthreads();   // BA: attn visible to all waves

        // P6: HV + aggregation; wave w = cols 32w..+31 (head h == w), all 4 nodes
        #pragma unroll
        for (int n_ = 0; n_ < 4; ++n_) {
            short8 c0[4], c1[4];
            #pragma unroll
            for (int kk = 0; kk < 4; ++kk) {
                c0[kk] = *(const short8*)&sm.sE[(n_ * 32 + l15) * ESTR + kk * 32 + quad * 8];
                c1[kk] = *(const short8*)&sm.sE[(n_ * 32 + 16 + l15) * ESTR + kk * 32 + quad * 8];
            }
            const float* ap = &sm.sS[(n_ * 4 + w) * SSTR];
            const float ainv = ap[33];
            #pragma unroll
            for (int ct2 = 0; ct2 < 2; ++ct2) {
                f32x4 av0 = {0.f,0.f,0.f,0.f}, av1 = {0.f,0.f,0.f,0.f};
                #pragma unroll
                for (int kk = 0; kk < 4; ++kk) {
                    av0 = __builtin_amdgcn_mfma_f32_16x16x32_bf16(c0[kk], bv[ct2][kk], av0, 0, 0, 0);
                    av1 = __builtin_amdgcn_mfma_f32_16x16x32_bf16(c1[kk], bv[ct2][kk], av1, 0, 0, 0);
                }
                float sum = 0.f, mx = NEGI;
                #pragma unroll
                for (int r = 0; r < 4; ++r) {
                    const float p0 = ap[quad * 4 + r]      * av0[r];
                    const float p1 = ap[16 + quad * 4 + r] * av1[r];
                    sum += p0 + p1;
                    mx = fmaxf(mx, fmaxf(p0, p1));
                }
                sum += __shfl_xor(sum, 16);
                sum += __shfl_xor(sum, 32);
                mx = fmaxf(mx, __shfl_xor(mx, 16));
                mx = fmaxf(mx, __shfl_xor(mx, 32));
                if (quad == 0) {
                    const int c = (2 * w + ct2) * 16 + l15;
                    const size_t ng = (size_t)(nb + s * 4 + n_) * 384;
                    catG[ng + c]       = f2bf(sum * ainv);  // mean
                    catG[ng + 128 + c] = f2bf(sum);         // sum
                    catG[ng + 256 + c] = f2bf(mx);          // max
                }
            }
        }
        __syncthreads();   // BB: all sE reads done

        if (s < NST - 1) {
            writeE<FP32>(sm.sE, tid, eF, eB);   // sE := E[s+1] (vmcnt here)
            { const int row = tid >> 4, cc = tid & 15;
              *(short8*)&sm.sTb[(s + 1) & 1][row * ESTR + cc * 8] = eT; }
            if (s < NST - 2) {
                issueE<FP32>(hE, ebase + (size_t)(s + 2) * 128 * 128, tid, eF, eB);
                eT = *(const short8*)(Tg + (size_t)(nb + (s + 2) * 4) * 512 + tid * 8);
                __builtin_amdgcn_sched_barrier(0);
            }
            __syncthreads();   // BC: next subtile staged
        }
    }
}

__global__ __launch_bounds__(256, 3)
void naB(const void* __restrict__ hE, const int* __restrict__ mask,
         const void* __restrict__ WV, const short* __restrict__ Tg,
         short* __restrict__ catG)
{
    __shared__ SmemB sm;
    if (detect_fp32((const short*)WV)) naB_body<true >(sm, hE, mask, WV, Tg, catG);
    else                               naB_body<false>(sm, hE, mask, WV, Tg, catG);
}

// ===================== kernel C: out = cat @ WO^T, 64 nodes/block ============
#define CNPB 64
struct alignas(16) SmemC {
    short sCat[CNPB * 392];   // 50176 B -> 3 blocks/CU
};

template<bool FP32>
__device__ __forceinline__ void naC_body(SmemC& sm, const short* __restrict__ catG,
    const void* __restrict__ WO, void* __restrict__ out)
{
    const int tid = threadIdx.x, lane = tid & 63, w = tid >> 6;
    const int quad = lane >> 4, l15 = lane & 15;
    const int nb = blockIdx.x * CNPB;

    // stage cat (coalesced): 3072 chunks of 8 bf16, 12 per thread
    #pragma unroll
    for (int it = 0; it < 12; ++it) {
        const int chunk = it * 256 + tid;
        const int row = chunk / 48, cc = chunk % 48;
        *(short8*)&sm.sCat[row * 392 + cc * 8] =
            *(const short8*)&catG[(size_t)nb * 384 + (size_t)chunk * 8];
    }

    // WO frags: loaded ONCE per wave, reused across 4 M-tiles (requests /4)
    short8 wo0[12], wo1[12];
    #pragma unroll
    for (int kk = 0; kk < 12; ++kk) {
        wo0[kk] = load8bf<FP32>(WO, (size_t)(w * 32 + l15) * 384 + kk * 32 + quad * 8);
        wo1[kk] = load8bf<FP32>(WO, (size_t)(w * 32 + 16 + l15) * 384 + kk * 32 + quad * 8);
    }
    __syncthreads();

    #pragma unroll
    for (int mt = 0; mt < 4; ++mt) {
        f32x4 o0 = {0.f,0.f,0.f,0.f}, o1 = {0.f,0.f,0.f,0.f};
        #pragma unroll
        for (int kk = 0; kk < 12; ++kk) {
            const short8 a = *(const short8*)&sm.sCat[(mt * 16 + l15) * 392 + kk * 32 + quad * 8];
            o0 = __builtin_amdgcn_mfma_f32_16x16x32_bf16(a, wo0[kk], o0, 0, 0, 0);
            o1 = __builtin_amdgcn_mfma_f32_16x16x32_bf16(a, wo1[kk], o1, 0, 0, 0);
        }
        #pragma unroll
        for (int r = 0; r < 4; ++r) {
            const int node = mt * 16 + quad * 4 + r;
            const size_t base = (size_t)(nb + node) * CDIM + w * 32;
            if constexpr (FP32) {
                ((float*)out)[base + l15]      = o0[r];
                ((float*)out)[base + 16 + l15] = o1[r];
            } else {
                ((short*)out)[base + l15]      = f2bf(o0[r]);
                ((short*)out)[base + 16 + l15] = f2bf(o1[r]);
            }
        }
    }
}

__global__ __launch_bounds__(256, 3)
void naC(const short* __restrict__ catG, const void* __restrict__ WO,
         void* __restrict__ out)
{
    __shared__ SmemC sm;
    if (detect_fp32((const short*)WO)) naC_body<true >(sm, catG, WO, out);
    else                               naC_body<false>(sm, catG, WO, out);
}

extern "C" void kernel_launch(void* const* d_in, const int* in_sizes, int n_in,
                              void* d_out, int out_size, void* d_ws, size_t ws_size,
                              hipStream_t stream) {
    (void)in_sizes; (void)n_in; (void)ws_size; (void)out_size;
    const void* hX   = d_in[0];
    const void* hE   = d_in[1];
    const int*  mask = (const int*)d_in[2];
    const void* WQ   = d_in[3];
    const void* WK   = d_in[4];
    const void* WV   = d_in[5];
    const void* WO   = d_in[6];

    short* Tg   = (short*)d_ws;                             // 16384*512*2 = 16.8 MB
    short* catG = (short*)((char*)d_ws + (32u << 20));      // 16384*384*2 = 12.6 MB

    naA<<<dim3(256), dim3(256), 0, stream>>>(hX, WQ, WK, Tg);
    naB<<<dim3(512), dim3(256), 0, stream>>>(hE, mask, WV, Tg, catG);
    naC<<<dim3(256), dim3(256), 0, stream>>>(catG, WO, d_out);
}

// Round 8
// 401.226 us; speedup vs baseline: 1.2327x; 1.0800x over previous
//
#include <hip/hip_runtime.h>
#include <hip/hip_bf16.h>
#include <stdint.h>

// NeighborAttention, MI355X gfx950 — round 8: r3 monolith (session-best) with
// the three measured critical-path fixes from later rounds.
// B=4,N=4096,K=32,C=128,H=4,d=32. One block = 16 nodes, 256 threads (4 waves),
// grid 1024. E streamed in 4 subtiles (128x128), 1-deep pinned reg prefetch.
// Fixes vs r3: (1) wave-parallel in-register softmax (r5-verified) replaces
// 16-thread serial loops; (2) all fp32->bf16 staging via v_cvt_pk_bf16_f32
// (__float22bfloat162_rn) — 4x fewer VALU ops in the exposed writeE window;
// (3) sched_barrier(0) pins the E prefetch (r4: unpinned loads get sunk).
// Structure kept from r3: block-lifetime WV frags, wave=col-tile P6, sCat in
// LDS, fused WO epilogue. LDS 73472 B -> 2 blocks/CU.

typedef __attribute__((ext_vector_type(8))) short short8;   // 8 bf16 = 16 B
typedef __attribute__((ext_vector_type(4))) float f32x4;

#define NPB   16
#define CDIM  128
#define KN    32
#define ESTR  136   // sE/sT/sQ row stride (bf16 units)
#define CATS  392   // sCat row stride (bf16 units)
#define SSTR  36    // attn row stride (fp32), 32 attn + [33]=ainv
#define NEGI  -3.0e38f

__device__ __forceinline__ float bf2f(short s) {
    union { unsigned int u; float f; } v;
    v.u = ((unsigned int)(unsigned short)s) << 16;
    return v.f;
}
__device__ __forceinline__ short f2bf(float f) {   // RNE, scalar (epilogue only)
    union { float ff; unsigned int u; } v; v.ff = f;
    unsigned int u = v.u;
    u += 0x7FFFu + ((u >> 16) & 1u);
    return (short)(u >> 16);
}

// 8 x fp32 -> 8 x bf16 via packed cvt (v_cvt_pk_bf16_f32), RNE
__device__ __forceinline__ short8 cvt8(const f32x4& a, const f32x4& b) {
    union { __hip_bfloat162 h; unsigned int u; } c0, c1, c2, c3;
    c0.h = __float22bfloat162_rn(float2{a[0], a[1]});
    c1.h = __float22bfloat162_rn(float2{a[2], a[3]});
    c2.h = __float22bfloat162_rn(float2{b[0], b[1]});
    c3.h = __float22bfloat162_rn(float2{b[2], b[3]});
    short8 r;
    r[0] = (short)(c0.u & 0xffff); r[1] = (short)(c0.u >> 16);
    r[2] = (short)(c1.u & 0xffff); r[3] = (short)(c1.u >> 16);
    r[4] = (short)(c2.u & 0xffff); r[5] = (short)(c2.u >> 16);
    r[6] = (short)(c3.u & 0xffff); r[7] = (short)(c3.u >> 16);
    return r;
}

template<bool FP32>
__device__ __forceinline__ short8 load8bf(const void* p, size_t idx) {
    if constexpr (FP32) {
        const float* fp = (const float*)p + idx;
        f32x4 a = *(const f32x4*)fp;
        f32x4 b = *(const f32x4*)(fp + 4);
        return cvt8(a, b);
    } else {
        return *(const short8*)((const short*)p + idx);
    }
}

template<bool FP32>
__device__ __forceinline__ short loadbf1(const void* p, size_t idx) {
    if constexpr (FP32) return f2bf(((const float*)p)[idx]);
    else return ((const short*)p)[idx];
}

// in-kernel dtype detect: fp32 low half-words decode to wild/NaN bf16s
__device__ __forceinline__ bool detect_fp32(const short* wp) {
    const int lane = threadIdx.x & 63;
    int cnt = 0;
    #pragma unroll
    for (int i = 0; i < 8; ++i) {
        const float v = bf2f(wp[lane + i * 64]);
        if (!(fabsf(v) < 8.0f)) cnt++;
    }
    #pragma unroll
    for (int d = 1; d < 64; d <<= 1) cnt += __shfl_xor(cnt, d);
    return cnt > 16;
}

struct alignas(16) Smem {
    short sE[128 * ESTR];     // 34816 B  E subtile (bf16)
    short sT[64 * ESTR];      // 17408 B  t = (q·Wk)*scale (bf16) [nh][ci]
    short sQ[16 * ESTR];      //  4352 B  q rows (bf16)
    short sCat[16 * CATS];    // 12544 B  [mean|sum|max] per node (bf16)
    float sS[16 * SSTR];      //  2304 B  attn rows (+[33]=ainv), per subtile
    int   sMask[NPB * KN];    //  2048 B
};                            // 73472 B -> 2 blocks/CU

template<bool FP32>
__device__ __forceinline__ void issueE(const void* hE, size_t base, int tid,
                                       f32x4 (&eF)[8][2], short8 (&eB)[8]) {
    if constexpr (FP32) {
        #pragma unroll
        for (int it = 0; it < 8; ++it) {
            const float* p = (const float*)hE + base + (size_t)(it * 256 + tid) * 8;
            eF[it][0] = *(const f32x4*)p;
            eF[it][1] = *(const f32x4*)(p + 4);
        }
    } else {
        #pragma unroll
        for (int it = 0; it < 8; ++it)
            eB[it] = *(const short8*)((const short*)hE + base + (size_t)(it * 256 + tid) * 8);
    }
    __builtin_amdgcn_sched_barrier(0);   // pin: loads must not be sunk (r3/r4)
}

template<bool FP32>
__device__ __forceinline__ void writeE(short* sE, int tid,
                                       const f32x4 (&eF)[8][2], const short8 (&eB)[8]) {
    #pragma unroll
    for (int it = 0; it < 8; ++it) {
        const int chunk = it * 256 + tid, row = chunk >> 4, cc = chunk & 15;
        short8 v;
        if constexpr (FP32) v = cvt8(eF[it][0], eF[it][1]);
        else                v = eB[it];
        *(short8*)&sE[row * ESTR + cc * 8] = v;
    }
}

template<bool FP32>
__device__ __forceinline__ void na_body(Smem& sm,
    const void* __restrict__ hX, const void* __restrict__ hE,
    const int* __restrict__ mask, const void* __restrict__ WQ,
    const void* __restrict__ WK, const void* __restrict__ WV,
    const void* __restrict__ WO, void* __restrict__ out)
{
    const int tid  = threadIdx.x;
    const int lane = tid & 63;
    const int w    = tid >> 6;      // wave 0..3
    const int quad = lane >> 4;
    const int l15  = lane & 15;
    const int nb   = blockIdx.x * NPB;
    const size_t ebase = (size_t)nb * (KN * CDIM);

    // ---- issue E subtile-0 prefetch first (hidden under prologue) ----
    f32x4 eF[8][2]; short8 eB[8];
    issueE<FP32>(hE, ebase, tid, eF, eB);

    // ---- stage mask (coalesced, 2 ints/thread) ----
    *(int2*)&sm.sMask[tid * 2] = *(const int2*)&mask[(size_t)nb * KN + tid * 2];

    // ---- X A-frags (row l15 = node) + WQ B-frags ----
    short8 ax[4];
    #pragma unroll
    for (int kk = 0; kk < 4; ++kk)
        ax[kk] = load8bf<FP32>(hX, (size_t)(nb + l15) * CDIM + kk * 32 + quad * 8);
    short8 bq[2][4];
    #pragma unroll
    for (int t2 = 0; t2 < 2; ++t2)
        #pragma unroll
        for (int kk = 0; kk < 4; ++kk)
            bq[t2][kk] = load8bf<FP32>(WQ, (size_t)(w * 32 + t2 * 16 + l15) * CDIM + kk * 32 + quad * 8);

    // ---- q = X @ WQ^T via MFMA -> sQ (bf16) ----
    {
        f32x4 o0 = {0.f,0.f,0.f,0.f}, o1 = {0.f,0.f,0.f,0.f};
        #pragma unroll
        for (int kk = 0; kk < 4; ++kk) {
            o0 = __builtin_amdgcn_mfma_f32_16x16x32_bf16(ax[kk], bq[0][kk], o0, 0, 0, 0);
            o1 = __builtin_amdgcn_mfma_f32_16x16x32_bf16(ax[kk], bq[1][kk], o1, 0, 0, 0);
        }
        #pragma unroll
        for (int r = 0; r < 4; ++r) {
            const int n = quad * 4 + r;                       // C row = node
            sm.sQ[n * ESTR + w * 32 + l15]      = f2bf(o0[r]);
            sm.sQ[n * ESTR + w * 32 + 16 + l15] = f2bf(o1[r]);
        }
    }
    __syncthreads();   // B1: sQ + sMask ready

    // ---- WK B-frags (gather; after q-gemm to cut peak VGPR) ----
    short8 bk[2][4];
    #pragma unroll
    for (int t2 = 0; t2 < 2; ++t2)
        #pragma unroll
        for (int kk = 0; kk < 4; ++kk) {
            const int j = w * 32 + t2 * 16 + l15;
            short8 b;
            #pragma unroll
            for (int jj = 0; jj < 8; ++jj)
                b[jj] = loadbf1<FP32>(WK, (size_t)(kk * 32 + quad * 8 + jj) * CDIM + j);
            bk[t2][kk] = b;
        }

    // ---- t = (q · WK)*scale via masked-head MFMA -> sT (bf16) ----
    {
        const float scale = 0.17677669529663687f;   // 1/sqrt(32)
        const short8 zz = {0,0,0,0,0,0,0,0};
        #pragma unroll
        for (int m = 0; m < 4; ++m) {
            const int n_g = m * 4 + (l15 >> 2), h_ = l15 & 3;
            const short8 qv = *(const short8*)&sm.sQ[n_g * ESTR + h_ * 32 + quad * 8];
            f32x4 c0 = {0.f,0.f,0.f,0.f}, c1 = {0.f,0.f,0.f,0.f};
            #pragma unroll
            for (int kk = 0; kk < 4; ++kk) {
                const short8 af = (kk == h_) ? qv : zz;
                c0 = __builtin_amdgcn_mfma_f32_16x16x32_bf16(af, bk[0][kk], c0, 0, 0, 0);
                c1 = __builtin_amdgcn_mfma_f32_16x16x32_bf16(af, bk[1][kk], c1, 0, 0, 0);
            }
            #pragma unroll
            for (int r = 0; r < 4; ++r) {
                const int row = m * 16 + quad * 4 + r;        // (n,h) row
                sm.sT[row * ESTR + w * 32 + l15]      = f2bf(c0[r] * scale);
                sm.sT[row * ESTR + w * 32 + 16 + l15] = f2bf(c1[r] * scale);
            }
        }
    }

    // ---- WV B-frags, block lifetime (wave w owns channel cols 32w..+31) ----
    short8 bv[2][4];
    #pragma unroll
    for (int ct2 = 0; ct2 < 2; ++ct2)
        #pragma unroll
        for (int kk = 0; kk < 4; ++kk)
            bv[ct2][kk] = load8bf<FP32>(WV, (size_t)((2 * w + ct2) * 16 + l15) * CDIM + kk * 32 + quad * 8);

    // ---- write E0 to sE; issue E1 (pinned) ----
    writeE<FP32>(sm.sE, tid, eF, eB);
    issueE<FP32>(hE, ebase + 1 * 128 * 128, tid, eF, eB);
    __syncthreads();   // B2: sT + sE(0) ready

    // ================= subtile loop (4 nodes each) =================
    #pragma unroll 1
    for (int s = 0; s < 4; ++s) {
        // ---- P4: scores = E·t^T (cols l15=(n,h); all computed, n==w kept) ----
        short8 bs[4], a0[4], a1[4];
        #pragma unroll
        for (int kk = 0; kk < 4; ++kk) {
            bs[kk] = *(const short8*)&sm.sT[(16 * s + l15) * ESTR + kk * 32 + quad * 8];
            a0[kk] = *(const short8*)&sm.sE[(w * 32 + l15) * ESTR + kk * 32 + quad * 8];
            a1[kk] = *(const short8*)&sm.sE[(w * 32 + 16 + l15) * ESTR + kk * 32 + quad * 8];
        }
        f32x4 s0 = {0.f,0.f,0.f,0.f}, s1 = {0.f,0.f,0.f,0.f};
        #pragma unroll
        for (int kk = 0; kk < 4; ++kk) {
            s0 = __builtin_amdgcn_mfma_f32_16x16x32_bf16(a0[kk], bs[kk], s0, 0, 0, 0);
            s1 = __builtin_amdgcn_mfma_f32_16x16x32_bf16(a1[kk], bs[kk], s1, 0, 0, 0);
        }

        // ---- in-register masked softmax (r5-verified), owner lanes publish ----
        {
            const int* mp = &sm.sMask[(s * 4 + (l15 >> 2)) * KN];
            float x[8]; int mk[8];
            #pragma unroll
            for (int j = 0; j < 4; ++j) {
                x[j] = s0[j];     mk[j]     = mp[quad * 4 + j];
                x[4 + j] = s1[j]; mk[4 + j] = mp[16 + quad * 4 + j];
            }
            float m = NEGI;
            #pragma unroll
            for (int j = 0; j < 8; ++j) m = fmaxf(m, (mk[j] > 0) ? x[j] : NEGI);
            m = fmaxf(m, __shfl_xor(m, 16));
            m = fmaxf(m, __shfl_xor(m, 32));
            float dsum = 0.f;
            #pragma unroll
            for (int j = 0; j < 8; ++j) {
                const float e = __expf(fminf(x[j] - m, 0.f)) * ((mk[j] > 0) ? 1.f : 0.f);
                x[j] = e; dsum += e;
            }
            dsum += __shfl_xor(dsum, 16);
            dsum += __shfl_xor(dsum, 32);
            const float inv = (dsum > 0.f) ? (1.f / dsum) : 0.f;
            if ((l15 >> 2) == w) {
                float* sp = &sm.sS[(w * 4 + (l15 & 3)) * SSTR];
                #pragma unroll
                for (int j = 0; j < 4; ++j) {
                    sp[quad * 4 + j]      = x[j] * inv;
                    sp[16 + quad * 4 + j] = x[4 + j] * inv;
                }
                if (quad == 0)
                    sp[33] = 1.0f / (((dsum > 0.f) ? 1.0f : 0.0f) + 1e-8f);
            }
        }
        __syncthreads();   // BA: attn visible

        // ---- P6: HV + aggregation; wave w = cols 32w..+31 (h == w), 4 nodes ----
        #pragma unroll
        for (int n_ = 0; n_ < 4; ++n_) {
            short8 c0[4], c1[4];
            #pragma unroll
            for (int kk = 0; kk < 4; ++kk) {
                c0[kk] = *(const short8*)&sm.sE[(n_ * 32 + l15) * ESTR + kk * 32 + quad * 8];
                c1[kk] = *(const short8*)&sm.sE[(n_ * 32 + 16 + l15) * ESTR + kk * 32 + quad * 8];
            }
            const float* ap = &sm.sS[(n_ * 4 + w) * SSTR];
            const float ainv = ap[33];
            #pragma unroll
            for (int ct2 = 0; ct2 < 2; ++ct2) {
                f32x4 av0 = {0.f,0.f,0.f,0.f}, av1 = {0.f,0.f,0.f,0.f};
                #pragma unroll
                for (int kk = 0; kk < 4; ++kk) {
                    av0 = __builtin_amdgcn_mfma_f32_16x16x32_bf16(c0[kk], bv[ct2][kk], av0, 0, 0, 0);
                    av1 = __builtin_amdgcn_mfma_f32_16x16x32_bf16(c1[kk], bv[ct2][kk], av1, 0, 0, 0);
                }
                float sum = 0.f, mx = NEGI;
                #pragma unroll
                for (int r = 0; r < 4; ++r) {
                    const float p0 = ap[quad * 4 + r]      * av0[r];
                    const float p1 = ap[16 + quad * 4 + r] * av1[r];
                    sum += p0 + p1;
                    mx = fmaxf(mx, fmaxf(p0, p1));
                }
                sum += __shfl_xor(sum, 16);
                sum += __shfl_xor(sum, 32);
                mx = fmaxf(mx, __shfl_xor(mx, 16));
                mx = fmaxf(mx, __shfl_xor(mx, 32));
                if (quad == 0) {
                    const int c = (2 * w + ct2) * 16 + l15, row = s * 4 + n_;
                    sm.sCat[row * CATS + c]       = f2bf(sum * ainv);  // mean
                    sm.sCat[row * CATS + 128 + c] = f2bf(sum);         // sum
                    sm.sCat[row * CATS + 256 + c] = f2bf(mx);          // max
                }
            }
        }
        __syncthreads();   // BB: all sE reads + sCat writes done

        if (s < 3) {
            writeE<FP32>(sm.sE, tid, eF, eB);   // sE := E[s+1] (cvt_pk path)
            if (s < 2) issueE<FP32>(hE, ebase + (size_t)(s + 2) * 128 * 128, tid, eF, eB);
            __syncthreads();   // BC: next subtile staged
        }
    }

    // ---- P7: out = cat @ WO^T via MFMA (M=16, K=384, wave owns 32 cols) ----
    {
        f32x4 o0 = {0.f,0.f,0.f,0.f}, o1 = {0.f,0.f,0.f,0.f};
        #pragma unroll
        for (int kk = 0; kk < 12; ++kk) {
            const short8 a  = *(const short8*)&sm.sCat[l15 * CATS + kk * 32 + quad * 8];
            const short8 b0 = load8bf<FP32>(WO, (size_t)(w * 32 + l15) * 384 + kk * 32 + quad * 8);
            const short8 b1 = load8bf<FP32>(WO, (size_t)(w * 32 + 16 + l15) * 384 + kk * 32 + quad * 8);
            o0 = __builtin_amdgcn_mfma_f32_16x16x32_bf16(a, b0, o0, 0, 0, 0);
            o1 = __builtin_amdgcn_mfma_f32_16x16x32_bf16(a, b1, o1, 0, 0, 0);
        }
        #pragma unroll
        for (int r = 0; r < 4; ++r) {
            const int node = quad * 4 + r;
            const size_t base = (size_t)(nb + node) * CDIM + w * 32;
            if constexpr (FP32) {
                ((float*)out)[base + l15]      = o0[r];
                ((float*)out)[base + 16 + l15] = o1[r];
            } else {
                ((short*)out)[base + l15]      = f2bf(o0[r]);
                ((short*)out)[base + 16 + l15] = f2bf(o1[r]);
            }
        }
    }
}

__global__ __launch_bounds__(256, 2)
void na_fused(const void* __restrict__ hX, const void* __restrict__ hE,
              const int* __restrict__ mask, const void* __restrict__ WQ,
              const void* __restrict__ WK, const void* __restrict__ WV,
              const void* __restrict__ WO, void* __restrict__ out)
{
    __shared__ Smem sm;
    if (detect_fp32((const short*)WQ)) na_body<true >(sm, hX, hE, mask, WQ, WK, WV, WO, out);
    else                               na_body<false>(sm, hX, hE, mask, WQ, WK, WV, WO, out);
}

extern "C" void kernel_launch(void* const* d_in, const int* in_sizes, int n_in,
                              void* d_out, int out_size, void* d_ws, size_t ws_size,
                              hipStream_t stream) {
    (void)in_sizes; (void)n_in; (void)ws_size; (void)out_size; (void)d_ws;
    const void* hX   = d_in[0];
    const void* hE   = d_in[1];
    const int*  mask = (const int*)d_in[2];
    const void* WQ   = d_in[3];
    const void* WK   = d_in[4];
    const void* WV   = d_in[5];
    const void* WO   = d_in[6];

    na_fused<<<dim3(1024), dim3(256), 0, stream>>>(hX, hE, mask, WQ, WK, WV, WO, d_out);
}

// Round 9
// 398.188 us; speedup vs baseline: 1.2421x; 1.0076x over previous
//
#include <hip/hip_runtime.h>
#include <hip/hip_bf16.h>
#include <stdint.h>

// NeighborAttention, MI355X gfx950 — round 9: node-granular double-buffered
// pipeline, 1 barrier per node, attn entirely in registers (shfl), continuous
// 16 KB/iter HBM issue. B=4,N=4096,K=32,C=128,H=4,d=32.
// One block = 16 nodes, 256 threads (4 waves), grid 1024.
// Per node i: {scores+softmax (all-lane, reg-only) | writeE(buf^1 <- prefetch)
// | issue E(i+2) | PV+aggregate via shfl-redistributed attn} -> 1 barrier.
// E tile = 32 rows, double-buffered (2x8.7 KB). sS deleted; sQ overlaid under
// sCat. LDS 49.4 KB -> 3 blocks/CU. Prologue/epilogue = r8 verbatim.

typedef __attribute__((ext_vector_type(8))) short short8;   // 8 bf16 = 16 B
typedef __attribute__((ext_vector_type(4))) float f32x4;

#define NPB   16
#define CDIM  128
#define KN    32
#define ESTR  136   // LDS row stride (bf16 units)
#define CATS  392   // sCat row stride (bf16 units)
#define NEGI  -3.0e38f

__device__ __forceinline__ float bf2f(short s) {
    union { unsigned int u; float f; } v;
    v.u = ((unsigned int)(unsigned short)s) << 16;
    return v.f;
}
__device__ __forceinline__ short f2bf(float f) {   // RNE scalar
    union { float ff; unsigned int u; } v; v.ff = f;
    unsigned int u = v.u;
    u += 0x7FFFu + ((u >> 16) & 1u);
    return (short)(u >> 16);
}

// 8 x fp32 -> 8 x bf16 via packed cvt (v_cvt_pk_bf16_f32), RNE
__device__ __forceinline__ short8 cvt8(const f32x4& a, const f32x4& b) {
    union { __hip_bfloat162 h; unsigned int u; } c0, c1, c2, c3;
    c0.h = __float22bfloat162_rn(float2{a[0], a[1]});
    c1.h = __float22bfloat162_rn(float2{a[2], a[3]});
    c2.h = __float22bfloat162_rn(float2{b[0], b[1]});
    c3.h = __float22bfloat162_rn(float2{b[2], b[3]});
    short8 r;
    r[0] = (short)(c0.u & 0xffff); r[1] = (short)(c0.u >> 16);
    r[2] = (short)(c1.u & 0xffff); r[3] = (short)(c1.u >> 16);
    r[4] = (short)(c2.u & 0xffff); r[5] = (short)(c2.u >> 16);
    r[6] = (short)(c3.u & 0xffff); r[7] = (short)(c3.u >> 16);
    return r;
}

template<bool FP32>
__device__ __forceinline__ short8 load8bf(const void* p, size_t idx) {
    if constexpr (FP32) {
        const float* fp = (const float*)p + idx;
        f32x4 a = *(const f32x4*)fp;
        f32x4 b = *(const f32x4*)(fp + 4);
        return cvt8(a, b);
    } else {
        return *(const short8*)((const short*)p + idx);
    }
}

template<bool FP32>
__device__ __forceinline__ short loadbf1(const void* p, size_t idx) {
    if constexpr (FP32) return f2bf(((const float*)p)[idx]);
    else return ((const short*)p)[idx];
}

// in-kernel dtype detect: fp32 low half-words decode to wild/NaN bf16s
__device__ __forceinline__ bool detect_fp32(const short* wp) {
    const int lane = threadIdx.x & 63;
    int cnt = 0;
    #pragma unroll
    for (int i = 0; i < 8; ++i) {
        const float v = bf2f(wp[lane + i * 64]);
        if (!(fabsf(v) < 8.0f)) cnt++;
    }
    #pragma unroll
    for (int d = 1; d < 64; d <<= 1) cnt += __shfl_xor(cnt, d);
    return cnt > 16;
}

struct alignas(16) Smem {
    short sEb[2][32 * ESTR];   // 17408 B  double-buffered 32-row node tiles
    short sT[64 * ESTR];       // 17408 B  t = (q·Wk)*scale (bf16), row=(n,h)
    union {
        short sQ[16 * ESTR];   //  4352 B  q rows (prologue only)
        short sCat[16 * CATS]; // 12544 B  [mean|sum|max] (main loop + epilogue)
    } u;
    int   sMask[NPB * KN];     //  2048 B
};                             // 49408 B -> 3 blocks/CU

// issue loads for one 32x128 node tile (16 KB fp32 / 8 KB bf16), 64 B/thread
template<bool FP32>
__device__ __forceinline__ void issueN(const void* hE, size_t base, int tid,
                                       f32x4 (&pF)[2][2], short8 (&pB)[2]) {
    if constexpr (FP32) {
        #pragma unroll
        for (int it = 0; it < 2; ++it) {
            const float* p = (const float*)hE + base + (size_t)(it * 256 + tid) * 8;
            pF[it][0] = *(const f32x4*)p;
            pF[it][1] = *(const f32x4*)(p + 4);
        }
    } else {
        #pragma unroll
        for (int it = 0; it < 2; ++it)
            pB[it] = *(const short8*)((const short*)hE + base + (size_t)(it * 256 + tid) * 8);
    }
    __builtin_amdgcn_sched_barrier(0);   // pin issue position (r4-proven)
}

template<bool FP32>
__device__ __forceinline__ void writeN(short* dst, int tid,
                                       const f32x4 (&pF)[2][2], const short8 (&pB)[2]) {
    #pragma unroll
    for (int it = 0; it < 2; ++it) {
        const int chunk = it * 256 + tid, row = chunk >> 4, cc = chunk & 15;
        short8 v;
        if constexpr (FP32) v = cvt8(pF[it][0], pF[it][1]);
        else                v = pB[it];
        *(short8*)&dst[row * ESTR + cc * 8] = v;
    }
}

template<bool FP32>
__device__ __forceinline__ void na_body(Smem& sm,
    const void* __restrict__ hX, const void* __restrict__ hE,
    const int* __restrict__ mask, const void* __restrict__ WQ,
    const void* __restrict__ WK, const void* __restrict__ WV,
    const void* __restrict__ WO, void* __restrict__ out)
{
    const int tid  = threadIdx.x;
    const int lane = tid & 63;
    const int w    = tid >> 6;      // wave 0..3 == head owner in PV
    const int quad = lane >> 4;
    const int l15  = lane & 15;
    const int nb   = blockIdx.x * NPB;
    const size_t ebase = (size_t)nb * (KN * CDIM);

    // ---- issue E(node 0) prefetch first ----
    f32x4 pF[2][2]; short8 pB[2];
    issueN<FP32>(hE, ebase, tid, pF, pB);

    // ---- stage mask (coalesced, 2 ints/thread) ----
    *(int2*)&sm.sMask[tid * 2] = *(const int2*)&mask[(size_t)nb * KN + tid * 2];

    // ---- X A-frags + WQ B-frags; q = X @ WQ^T -> u.sQ ----
    short8 ax[4];
    #pragma unroll
    for (int kk = 0; kk < 4; ++kk)
        ax[kk] = load8bf<FP32>(hX, (size_t)(nb + l15) * CDIM + kk * 32 + quad * 8);
    short8 bq[2][4];
    #pragma unroll
    for (int t2 = 0; t2 < 2; ++t2)
        #pragma unroll
        for (int kk = 0; kk < 4; ++kk)
            bq[t2][kk] = load8bf<FP32>(WQ, (size_t)(w * 32 + t2 * 16 + l15) * CDIM + kk * 32 + quad * 8);
    {
        f32x4 o0 = {0.f,0.f,0.f,0.f}, o1 = {0.f,0.f,0.f,0.f};
        #pragma unroll
        for (int kk = 0; kk < 4; ++kk) {
            o0 = __builtin_amdgcn_mfma_f32_16x16x32_bf16(ax[kk], bq[0][kk], o0, 0, 0, 0);
            o1 = __builtin_amdgcn_mfma_f32_16x16x32_bf16(ax[kk], bq[1][kk], o1, 0, 0, 0);
        }
        #pragma unroll
        for (int r = 0; r < 4; ++r) {
            const int n = quad * 4 + r;
            sm.u.sQ[n * ESTR + w * 32 + l15]      = f2bf(o0[r]);
            sm.u.sQ[n * ESTR + w * 32 + 16 + l15] = f2bf(o1[r]);
        }
    }
    __syncthreads();   // B1: sQ + sMask ready

    // ---- WK B-frags (gather) ; t = (q·WK)*scale -> sT (row=(n,h)) ----
    short8 bk[2][4];
    #pragma unroll
    for (int t2 = 0; t2 < 2; ++t2)
        #pragma unroll
        for (int kk = 0; kk < 4; ++kk) {
            const int j = w * 32 + t2 * 16 + l15;
            short8 b;
            #pragma unroll
            for (int jj = 0; jj < 8; ++jj)
                b[jj] = loadbf1<FP32>(WK, (size_t)(kk * 32 + quad * 8 + jj) * CDIM + j);
            bk[t2][kk] = b;
        }
    {
        const float scale = 0.17677669529663687f;   // 1/sqrt(32)
        const short8 zz = {0,0,0,0,0,0,0,0};
        #pragma unroll
        for (int m = 0; m < 4; ++m) {
            const int n_g = m * 4 + (l15 >> 2), h_ = l15 & 3;
            const short8 qv = *(const short8*)&sm.u.sQ[n_g * ESTR + h_ * 32 + quad * 8];
            f32x4 c0 = {0.f,0.f,0.f,0.f}, c1 = {0.f,0.f,0.f,0.f};
            #pragma unroll
            for (int kk = 0; kk < 4; ++kk) {
                const short8 af = (kk == h_) ? qv : zz;
                c0 = __builtin_amdgcn_mfma_f32_16x16x32_bf16(af, bk[0][kk], c0, 0, 0, 0);
                c1 = __builtin_amdgcn_mfma_f32_16x16x32_bf16(af, bk[1][kk], c1, 0, 0, 0);
            }
            #pragma unroll
            for (int r = 0; r < 4; ++r) {
                const int row = m * 16 + quad * 4 + r;        // (n,h) row
                sm.sT[row * ESTR + w * 32 + l15]      = f2bf(c0[r] * scale);
                sm.sT[row * ESTR + w * 32 + 16 + l15] = f2bf(c1[r] * scale);
            }
        }
    }

    // ---- WV B-frags (block lifetime, wave w owns channel cols 32w..+31) ----
    short8 bv[2][4];
    #pragma unroll
    for (int ct2 = 0; ct2 < 2; ++ct2)
        #pragma unroll
        for (int kk = 0; kk < 4; ++kk)
            bv[ct2][kk] = load8bf<FP32>(WV, (size_t)((2 * w + ct2) * 16 + l15) * CDIM + kk * 32 + quad * 8);

    // ---- stage node 0, issue node 1 ----
    writeN<FP32>(sm.sEb[0], tid, pF, pB);
    issueN<FP32>(hE, ebase + 1 * (KN * CDIM), tid, pF, pB);
    __syncthreads();   // B2: sT + sEb[0] + mask ready; pf = E(1) in flight

    // ================= node loop: 1 barrier per node =================
    #pragma unroll 1
    for (int i = 0; i < NPB; ++i) {
        const short* bufp = sm.sEb[i & 1];

        // ---- frags: A = node rows (reused for scores AND PV), B = t cols ----
        short8 a0[4], a1[4], bs[4];
        #pragma unroll
        for (int kk = 0; kk < 4; ++kk) {
            bs[kk] = *(const short8*)&sm.sT[(i * 4 + (l15 & 3)) * ESTR + kk * 32 + quad * 8];
            a0[kk] = *(const short8*)&bufp[l15 * ESTR + kk * 32 + quad * 8];
            a1[kk] = *(const short8*)&bufp[(16 + l15) * ESTR + kk * 32 + quad * 8];
        }

        // ---- scores: col l15 -> head l15&3 (4x replicated), row -> k ----
        f32x4 s0 = {0.f,0.f,0.f,0.f}, s1 = {0.f,0.f,0.f,0.f};
        #pragma unroll
        for (int kk = 0; kk < 4; ++kk) {
            s0 = __builtin_amdgcn_mfma_f32_16x16x32_bf16(a0[kk], bs[kk], s0, 0, 0, 0);
            s1 = __builtin_amdgcn_mfma_f32_16x16x32_bf16(a1[kk], bs[kk], s1, 0, 0, 0);
        }

        // ---- masked softmax, fully in-register (every lane has full column) ----
        float x[8], ainv;
        {
            const int* mp = &sm.sMask[i * KN];
            int mk[8];
            #pragma unroll
            for (int j = 0; j < 4; ++j) {
                x[j] = s0[j];     mk[j]     = mp[quad * 4 + j];
                x[4 + j] = s1[j]; mk[4 + j] = mp[16 + quad * 4 + j];
            }
            float m = NEGI;
            #pragma unroll
            for (int j = 0; j < 8; ++j) m = fmaxf(m, (mk[j] > 0) ? x[j] : NEGI);
            m = fmaxf(m, __shfl_xor(m, 16));
            m = fmaxf(m, __shfl_xor(m, 32));
            float dsum = 0.f;
            #pragma unroll
            for (int j = 0; j < 8; ++j) {
                const float e = __expf(fminf(x[j] - m, 0.f)) * ((mk[j] > 0) ? 1.f : 0.f);
                x[j] = e; dsum += e;
            }
            dsum += __shfl_xor(dsum, 16);
            dsum += __shfl_xor(dsum, 32);
            const float inv = (dsum > 0.f) ? (1.f / dsum) : 0.f;
            #pragma unroll
            for (int j = 0; j < 8; ++j) x[j] *= inv;
            ainv = 1.0f / (((dsum > 0.f) ? 1.0f : 0.0f) + 1e-8f);
        }

        // ---- stage next node into the other buffer; issue node i+2 ----
        if (i < NPB - 1) {
            writeN<FP32>(sm.sEb[(i + 1) & 1], tid, pF, pB);   // pf = E(i+1)
            if (i < NPB - 2)
                issueN<FP32>(hE, ebase + (size_t)(i + 2) * (KN * CDIM), tid, pF, pB);
        }

        // ---- PV + aggregation; attn pulled from lane (quad*16 + w) ----
        {
            const int src = (quad << 4) | w;     // lane holding head w, same quad
            float aA[4], aB[4];
            #pragma unroll
            for (int r = 0; r < 4; ++r) {
                aA[r] = __shfl(x[r], src);
                aB[r] = __shfl(x[4 + r], src);
            }
            const float ainvw = __shfl(ainv, src);
            #pragma unroll
            for (int ct2 = 0; ct2 < 2; ++ct2) {
                f32x4 av0 = {0.f,0.f,0.f,0.f}, av1 = {0.f,0.f,0.f,0.f};
                #pragma unroll
                for (int kk = 0; kk < 4; ++kk) {
                    av0 = __builtin_amdgcn_mfma_f32_16x16x32_bf16(a0[kk], bv[ct2][kk], av0, 0, 0, 0);
                    av1 = __builtin_amdgcn_mfma_f32_16x16x32_bf16(a1[kk], bv[ct2][kk], av1, 0, 0, 0);
                }
                float sum = 0.f, mx = NEGI;
                #pragma unroll
                for (int r = 0; r < 4; ++r) {
                    const float p0 = aA[r] * av0[r];
                    const float p1 = aB[r] * av1[r];
                    sum += p0 + p1;
                    mx = fmaxf(mx, fmaxf(p0, p1));
                }
                sum += __shfl_xor(sum, 16);
                sum += __shfl_xor(sum, 32);
                mx = fmaxf(mx, __shfl_xor(mx, 16));
                mx = fmaxf(mx, __shfl_xor(mx, 32));
                if (quad == 0) {
                    const int c = (2 * w + ct2) * 16 + l15;
                    sm.u.sCat[i * CATS + c]       = f2bf(sum * ainvw);  // mean
                    sm.u.sCat[i * CATS + 128 + c] = f2bf(sum);          // sum
                    sm.u.sCat[i * CATS + 256 + c] = f2bf(mx);           // max
                }
            }
        }
        __syncthreads();   // buf[(i+1)&1] staged + buf[i&1] reads done
    }

    // ---- P7: out = cat @ WO^T via MFMA (M=16, K=384, wave owns 32 cols) ----
    {
        f32x4 o0 = {0.f,0.f,0.f,0.f}, o1 = {0.f,0.f,0.f,0.f};
        #pragma unroll
        for (int kk = 0; kk < 12; ++kk) {
            const short8 a  = *(const short8*)&sm.u.sCat[l15 * CATS + kk * 32 + quad * 8];
            const short8 b0 = load8bf<FP32>(WO, (size_t)(w * 32 + l15) * 384 + kk * 32 + quad * 8);
            const short8 b1 = load8bf<FP32>(WO, (size_t)(w * 32 + 16 + l15) * 384 + kk * 32 + quad * 8);
            o0 = __builtin_amdgcn_mfma_f32_16x16x32_bf16(a, b0, o0, 0, 0, 0);
            o1 = __builtin_amdgcn_mfma_f32_16x16x32_bf16(a, b1, o1, 0, 0, 0);
        }
        #pragma unroll
        for (int r = 0; r < 4; ++r) {
            const int node = quad * 4 + r;
            const size_t base = (size_t)(nb + node) * CDIM + w * 32;
            if constexpr (FP32) {
                ((float*)out)[base + l15]      = o0[r];
                ((float*)out)[base + 16 + l15] = o1[r];
            } else {
                ((short*)out)[base + l15]      = f2bf(o0[r]);
                ((short*)out)[base + 16 + l15] = f2bf(o1[r]);
            }
        }
    }
}

__global__ __launch_bounds__(256, 3)
void na_fused(const void* __restrict__ hX, const void* __restrict__ hE,
              const int* __restrict__ mask, const void* __restrict__ WQ,
              const void* __restrict__ WK, const void* __restrict__ WV,
              const void* __restrict__ WO, void* __restrict__ out)
{
    __shared__ Smem sm;
    if (detect_fp32((const short*)WQ)) na_body<true >(sm, hX, hE, mask, WQ, WK, WV, WO, out);
    else                               na_body<false>(sm, hX, hE, mask, WQ, WK, WV, WO, out);
}

extern "C" void kernel_launch(void* const* d_in, const int* in_sizes, int n_in,
                              void* d_out, int out_size, void* d_ws, size_t ws_size,
                              hipStream_t stream) {
    (void)in_sizes; (void)n_in; (void)ws_size; (void)out_size; (void)d_ws;
    const void* hX   = d_in[0];
    const void* hE   = d_in[1];
    const int*  mask = (const int*)d_in[2];
    const void* WQ   = d_in[3];
    const void* WK   = d_in[4];
    const void* WV   = d_in[5];
    const void* WO   = d_in[6];

    na_fused<<<dim3(1024), dim3(256), 0, stream>>>(hX, hE, mask, WQ, WK, WV, WO, d_out);
}

// Round 10
// 397.494 us; speedup vs baseline: 1.2442x; 1.0017x over previous
//
#include <hip/hip_runtime.h>
#include <hip/hip_bf16.h>
#include <stdint.h>

// NeighborAttention, MI355X gfx950 — round 10: r9 + NON-DRAINING loop barrier.
// The only change vs r9: per-iteration __syncthreads() -> {s_waitcnt lgkmcnt(0);
// raw s_barrier; sched_barrier(0)}. __syncthreads forces vmcnt(0) which drained
// the E prefetch every iteration (the session-long serializer); the raw barrier
// lets prefetched global loads stay in flight across iterations (T4 pattern).
// B=4,N=4096,K=32,C=128,H=4,d=32. 16 nodes/block, 256 thr, grid 1024.
// LDS 49.4 KB -> 3 blocks/CU.

typedef __attribute__((ext_vector_type(8))) short short8;   // 8 bf16 = 16 B
typedef __attribute__((ext_vector_type(4))) float f32x4;

#define NPB   16
#define CDIM  128
#define KN    32
#define ESTR  136   // LDS row stride (bf16 units)
#define CATS  392   // sCat row stride (bf16 units)
#define NEGI  -3.0e38f

__device__ __forceinline__ float bf2f(short s) {
    union { unsigned int u; float f; } v;
    v.u = ((unsigned int)(unsigned short)s) << 16;
    return v.f;
}
__device__ __forceinline__ short f2bf(float f) {   // RNE scalar
    union { float ff; unsigned int u; } v; v.ff = f;
    unsigned int u = v.u;
    u += 0x7FFFu + ((u >> 16) & 1u);
    return (short)(u >> 16);
}

// 8 x fp32 -> 8 x bf16 via packed cvt (v_cvt_pk_bf16_f32), RNE
__device__ __forceinline__ short8 cvt8(const f32x4& a, const f32x4& b) {
    union { __hip_bfloat162 h; unsigned int u; } c0, c1, c2, c3;
    c0.h = __float22bfloat162_rn(float2{a[0], a[1]});
    c1.h = __float22bfloat162_rn(float2{a[2], a[3]});
    c2.h = __float22bfloat162_rn(float2{b[0], b[1]});
    c3.h = __float22bfloat162_rn(float2{b[2], b[3]});
    short8 r;
    r[0] = (short)(c0.u & 0xffff); r[1] = (short)(c0.u >> 16);
    r[2] = (short)(c1.u & 0xffff); r[3] = (short)(c1.u >> 16);
    r[4] = (short)(c2.u & 0xffff); r[5] = (short)(c2.u >> 16);
    r[6] = (short)(c3.u & 0xffff); r[7] = (short)(c3.u >> 16);
    return r;
}

template<bool FP32>
__device__ __forceinline__ short8 load8bf(const void* p, size_t idx) {
    if constexpr (FP32) {
        const float* fp = (const float*)p + idx;
        f32x4 a = *(const f32x4*)fp;
        f32x4 b = *(const f32x4*)(fp + 4);
        return cvt8(a, b);
    } else {
        return *(const short8*)((const short*)p + idx);
    }
}

template<bool FP32>
__device__ __forceinline__ short loadbf1(const void* p, size_t idx) {
    if constexpr (FP32) return f2bf(((const float*)p)[idx]);
    else return ((const short*)p)[idx];
}

// in-kernel dtype detect: fp32 low half-words decode to wild/NaN bf16s
__device__ __forceinline__ bool detect_fp32(const short* wp) {
    const int lane = threadIdx.x & 63;
    int cnt = 0;
    #pragma unroll
    for (int i = 0; i < 8; ++i) {
        const float v = bf2f(wp[lane + i * 64]);
        if (!(fabsf(v) < 8.0f)) cnt++;
    }
    #pragma unroll
    for (int d = 1; d < 64; d <<= 1) cnt += __shfl_xor(cnt, d);
    return cnt > 16;
}

struct alignas(16) Smem {
    short sEb[2][32 * ESTR];   // 17408 B  double-buffered 32-row node tiles
    short sT[64 * ESTR];       // 17408 B  t = (q·Wk)*scale (bf16), row=(n,h)
    union {
        short sQ[16 * ESTR];   //  4352 B  q rows (prologue only)
        short sCat[16 * CATS]; // 12544 B  [mean|sum|max] (main loop + epilogue)
    } u;
    int   sMask[NPB * KN];     //  2048 B
};                             // 49408 B -> 3 blocks/CU

// issue loads for one 32x128 node tile (16 KB fp32 / 8 KB bf16), 64 B/thread
template<bool FP32>
__device__ __forceinline__ void issueN(const void* hE, size_t base, int tid,
                                       f32x4 (&pF)[2][2], short8 (&pB)[2]) {
    if constexpr (FP32) {
        #pragma unroll
        for (int it = 0; it < 2; ++it) {
            const float* p = (const float*)hE + base + (size_t)(it * 256 + tid) * 8;
            pF[it][0] = *(const f32x4*)p;
            pF[it][1] = *(const f32x4*)(p + 4);
        }
    } else {
        #pragma unroll
        for (int it = 0; it < 2; ++it)
            pB[it] = *(const short8*)((const short*)hE + base + (size_t)(it * 256 + tid) * 8);
    }
    __builtin_amdgcn_sched_barrier(0);   // pin issue position (r4-proven)
}

template<bool FP32>
__device__ __forceinline__ void writeN(short* dst, int tid,
                                       const f32x4 (&pF)[2][2], const short8 (&pB)[2]) {
    #pragma unroll
    for (int it = 0; it < 2; ++it) {
        const int chunk = it * 256 + tid, row = chunk >> 4, cc = chunk & 15;
        short8 v;
        if constexpr (FP32) v = cvt8(pF[it][0], pF[it][1]);
        else                v = pB[it];
        *(short8*)&dst[row * ESTR + cc * 8] = v;
    }
}

template<bool FP32>
__device__ __forceinline__ void na_body(Smem& sm,
    const void* __restrict__ hX, const void* __restrict__ hE,
    const int* __restrict__ mask, const void* __restrict__ WQ,
    const void* __restrict__ WK, const void* __restrict__ WV,
    const void* __restrict__ WO, void* __restrict__ out)
{
    const int tid  = threadIdx.x;
    const int lane = tid & 63;
    const int w    = tid >> 6;      // wave 0..3 == head owner in PV
    const int quad = lane >> 4;
    const int l15  = lane & 15;
    const int nb   = blockIdx.x * NPB;
    const size_t ebase = (size_t)nb * (KN * CDIM);

    // ---- issue E(node 0) prefetch first ----
    f32x4 pF[2][2]; short8 pB[2];
    issueN<FP32>(hE, ebase, tid, pF, pB);

    // ---- stage mask (coalesced, 2 ints/thread) ----
    *(int2*)&sm.sMask[tid * 2] = *(const int2*)&mask[(size_t)nb * KN + tid * 2];

    // ---- X A-frags + WQ B-frags; q = X @ WQ^T -> u.sQ ----
    short8 ax[4];
    #pragma unroll
    for (int kk = 0; kk < 4; ++kk)
        ax[kk] = load8bf<FP32>(hX, (size_t)(nb + l15) * CDIM + kk * 32 + quad * 8);
    short8 bq[2][4];
    #pragma unroll
    for (int t2 = 0; t2 < 2; ++t2)
        #pragma unroll
        for (int kk = 0; kk < 4; ++kk)
            bq[t2][kk] = load8bf<FP32>(WQ, (size_t)(w * 32 + t2 * 16 + l15) * CDIM + kk * 32 + quad * 8);
    {
        f32x4 o0 = {0.f,0.f,0.f,0.f}, o1 = {0.f,0.f,0.f,0.f};
        #pragma unroll
        for (int kk = 0; kk < 4; ++kk) {
            o0 = __builtin_amdgcn_mfma_f32_16x16x32_bf16(ax[kk], bq[0][kk], o0, 0, 0, 0);
            o1 = __builtin_amdgcn_mfma_f32_16x16x32_bf16(ax[kk], bq[1][kk], o1, 0, 0, 0);
        }
        #pragma unroll
        for (int r = 0; r < 4; ++r) {
            const int n = quad * 4 + r;
            sm.u.sQ[n * ESTR + w * 32 + l15]      = f2bf(o0[r]);
            sm.u.sQ[n * ESTR + w * 32 + 16 + l15] = f2bf(o1[r]);
        }
    }
    __syncthreads();   // B1: sQ + sMask ready

    // ---- WK B-frags (gather) ; t = (q·WK)*scale -> sT (row=(n,h)) ----
    short8 bk[2][4];
    #pragma unroll
    for (int t2 = 0; t2 < 2; ++t2)
        #pragma unroll
        for (int kk = 0; kk < 4; ++kk) {
            const int j = w * 32 + t2 * 16 + l15;
            short8 b;
            #pragma unroll
            for (int jj = 0; jj < 8; ++jj)
                b[jj] = loadbf1<FP32>(WK, (size_t)(kk * 32 + quad * 8 + jj) * CDIM + j);
            bk[t2][kk] = b;
        }
    {
        const float scale = 0.17677669529663687f;   // 1/sqrt(32)
        const short8 zz = {0,0,0,0,0,0,0,0};
        #pragma unroll
        for (int m = 0; m < 4; ++m) {
            const int n_g = m * 4 + (l15 >> 2), h_ = l15 & 3;
            const short8 qv = *(const short8*)&sm.u.sQ[n_g * ESTR + h_ * 32 + quad * 8];
            f32x4 c0 = {0.f,0.f,0.f,0.f}, c1 = {0.f,0.f,0.f,0.f};
            #pragma unroll
            for (int kk = 0; kk < 4; ++kk) {
                const short8 af = (kk == h_) ? qv : zz;
                c0 = __builtin_amdgcn_mfma_f32_16x16x32_bf16(af, bk[0][kk], c0, 0, 0, 0);
                c1 = __builtin_amdgcn_mfma_f32_16x16x32_bf16(af, bk[1][kk], c1, 0, 0, 0);
            }
            #pragma unroll
            for (int r = 0; r < 4; ++r) {
                const int row = m * 16 + quad * 4 + r;        // (n,h) row
                sm.sT[row * ESTR + w * 32 + l15]      = f2bf(c0[r] * scale);
                sm.sT[row * ESTR + w * 32 + 16 + l15] = f2bf(c1[r] * scale);
            }
        }
    }

    // ---- WV B-frags (block lifetime, wave w owns channel cols 32w..+31) ----
    short8 bv[2][4];
    #pragma unroll
    for (int ct2 = 0; ct2 < 2; ++ct2)
        #pragma unroll
        for (int kk = 0; kk < 4; ++kk)
            bv[ct2][kk] = load8bf<FP32>(WV, (size_t)((2 * w + ct2) * 16 + l15) * CDIM + kk * 32 + quad * 8);

    // ---- stage node 0, issue node 1 ----
    writeN<FP32>(sm.sEb[0], tid, pF, pB);
    issueN<FP32>(hE, ebase + 1 * (KN * CDIM), tid, pF, pB);
    __syncthreads();   // B2: sT + sEb[0] + mask ready; pf = E(1) in flight
                       // (this drain costs one latency, once per block)

    // ================= node loop: 1 NON-DRAINING barrier per node ============
    #pragma unroll 1
    for (int i = 0; i < NPB; ++i) {
        const short* bufp = sm.sEb[i & 1];

        // ---- frags: A = node rows (reused for scores AND PV), B = t cols ----
        short8 a0[4], a1[4], bs[4];
        #pragma unroll
        for (int kk = 0; kk < 4; ++kk) {
            bs[kk] = *(const short8*)&sm.sT[(i * 4 + (l15 & 3)) * ESTR + kk * 32 + quad * 8];
            a0[kk] = *(const short8*)&bufp[l15 * ESTR + kk * 32 + quad * 8];
            a1[kk] = *(const short8*)&bufp[(16 + l15) * ESTR + kk * 32 + quad * 8];
        }

        // ---- scores: col l15 -> head l15&3 (4x replicated), row -> k ----
        f32x4 s0 = {0.f,0.f,0.f,0.f}, s1 = {0.f,0.f,0.f,0.f};
        #pragma unroll
        for (int kk = 0; kk < 4; ++kk) {
            s0 = __builtin_amdgcn_mfma_f32_16x16x32_bf16(a0[kk], bs[kk], s0, 0, 0, 0);
            s1 = __builtin_amdgcn_mfma_f32_16x16x32_bf16(a1[kk], bs[kk], s1, 0, 0, 0);
        }

        // ---- masked softmax, fully in-register (every lane has full column) ----
        float x[8], ainv;
        {
            const int* mp = &sm.sMask[i * KN];
            int mk[8];
            #pragma unroll
            for (int j = 0; j < 4; ++j) {
                x[j] = s0[j];     mk[j]     = mp[quad * 4 + j];
                x[4 + j] = s1[j]; mk[4 + j] = mp[16 + quad * 4 + j];
            }
            float m = NEGI;
            #pragma unroll
            for (int j = 0; j < 8; ++j) m = fmaxf(m, (mk[j] > 0) ? x[j] : NEGI);
            m = fmaxf(m, __shfl_xor(m, 16));
            m = fmaxf(m, __shfl_xor(m, 32));
            float dsum = 0.f;
            #pragma unroll
            for (int j = 0; j < 8; ++j) {
                const float e = __expf(fminf(x[j] - m, 0.f)) * ((mk[j] > 0) ? 1.f : 0.f);
                x[j] = e; dsum += e;
            }
            dsum += __shfl_xor(dsum, 16);
            dsum += __shfl_xor(dsum, 32);
            const float inv = (dsum > 0.f) ? (1.f / dsum) : 0.f;
            #pragma unroll
            for (int j = 0; j < 8; ++j) x[j] *= inv;
            ainv = 1.0f / (((dsum > 0.f) ? 1.0f : 0.0f) + 1e-8f);
        }

        // ---- stage next node into the other buffer; issue node i+2 ----
        // writeN's register deps give an automatic COUNTED vmcnt wait (only the
        // i+1 loads), then fresh i+2 loads go in flight and STAY in flight
        // across the raw barrier below.
        if (i < NPB - 1) {
            writeN<FP32>(sm.sEb[(i + 1) & 1], tid, pF, pB);   // pf = E(i+1)
            if (i < NPB - 2)
                issueN<FP32>(hE, ebase + (size_t)(i + 2) * (KN * CDIM), tid, pF, pB);
        }

        // ---- PV + aggregation; attn pulled from lane (quad*16 + w) ----
        {
            const int src = (quad << 4) | w;     // lane holding head w, same quad
            float aA[4], aB[4];
            #pragma unroll
            for (int r = 0; r < 4; ++r) {
                aA[r] = __shfl(x[r], src);
                aB[r] = __shfl(x[4 + r], src);
            }
            const float ainvw = __shfl(ainv, src);
            #pragma unroll
            for (int ct2 = 0; ct2 < 2; ++ct2) {
                f32x4 av0 = {0.f,0.f,0.f,0.f}, av1 = {0.f,0.f,0.f,0.f};
                #pragma unroll
                for (int kk = 0; kk < 4; ++kk) {
                    av0 = __builtin_amdgcn_mfma_f32_16x16x32_bf16(a0[kk], bv[ct2][kk], av0, 0, 0, 0);
                    av1 = __builtin_amdgcn_mfma_f32_16x16x32_bf16(a1[kk], bv[ct2][kk], av1, 0, 0, 0);
                }
                float sum = 0.f, mx = NEGI;
                #pragma unroll
                for (int r = 0; r < 4; ++r) {
                    const float p0 = aA[r] * av0[r];
                    const float p1 = aB[r] * av1[r];
                    sum += p0 + p1;
                    mx = fmaxf(mx, fmaxf(p0, p1));
                }
                sum += __shfl_xor(sum, 16);
                sum += __shfl_xor(sum, 32);
                mx = fmaxf(mx, __shfl_xor(mx, 16));
                mx = fmaxf(mx, __shfl_xor(mx, 32));
                if (quad == 0) {
                    const int c = (2 * w + ct2) * 16 + l15;
                    sm.u.sCat[i * CATS + c]       = f2bf(sum * ainvw);  // mean
                    sm.u.sCat[i * CATS + 128 + c] = f2bf(sum);          // sum
                    sm.u.sCat[i * CATS + 256 + c] = f2bf(mx);           // max
                }
            }
        }

        // ---- NON-DRAINING barrier (the round-10 change) ----
        // Own ds_writes visible (lgkmcnt only), rendezvous WITHOUT vmcnt(0):
        // the i+2 prefetch stays in flight across iterations.
        asm volatile("s_waitcnt lgkmcnt(0)" ::: "memory");
        __builtin_amdgcn_s_barrier();
        __builtin_amdgcn_sched_barrier(0);   // rule #18: no hoisting past barrier
    }
    __syncthreads();   // full drain before epilogue reads sCat

    // ---- P7: out = cat @ WO^T via MFMA (M=16, K=384, wave owns 32 cols) ----
    {
        f32x4 o0 = {0.f,0.f,0.f,0.f}, o1 = {0.f,0.f,0.f,0.f};
        #pragma unroll
        for (int kk = 0; kk < 12; ++kk) {
            const short8 a  = *(const short8*)&sm.u.sCat[l15 * CATS + kk * 32 + quad * 8];
            const short8 b0 = load8bf<FP32>(WO, (size_t)(w * 32 + l15) * 384 + kk * 32 + quad * 8);
            const short8 b1 = load8bf<FP32>(WO, (size_t)(w * 32 + 16 + l15) * 384 + kk * 32 + quad * 8);
            o0 = __builtin_amdgcn_mfma_f32_16x16x32_bf16(a, b0, o0, 0, 0, 0);
            o1 = __builtin_amdgcn_mfma_f32_16x16x32_bf16(a, b1, o1, 0, 0, 0);
        }
        #pragma unroll
        for (int r = 0; r < 4; ++r) {
            const int node = quad * 4 + r;
            const size_t base = (size_t)(nb + node) * CDIM + w * 32;
            if constexpr (FP32) {
                ((float*)out)[base + l15]      = o0[r];
                ((float*)out)[base + 16 + l15] = o1[r];
            } else {
                ((short*)out)[base + l15]      = f2bf(o0[r]);
                ((short*)out)[base + 16 + l15] = f2bf(o1[r]);
            }
        }
    }
}

__global__ __launch_bounds__(256, 3)
void na_fused(const void* __restrict__ hX, const void* __restrict__ hE,
              const int* __restrict__ mask, const void* __restrict__ WQ,
              const void* __restrict__ WK, const void* __restrict__ WV,
              const void* __restrict__ WO, void* __restrict__ out)
{
    __shared__ Smem sm;
    if (detect_fp32((const short*)WQ)) na_body<true >(sm, hX, hE, mask, WQ, WK, WV, WO, out);
    else                               na_body<false>(sm, hX, hE, mask, WQ, WK, WV, WO, out);
}

extern "C" void kernel_launch(void* const* d_in, const int* in_sizes, int n_in,
                              void* d_out, int out_size, void* d_ws, size_t ws_size,
                              hipStream_t stream) {
    (void)in_sizes; (void)n_in; (void)ws_size; (void)out_size; (void)d_ws;
    const void* hX   = d_in[0];
    const void* hE   = d_in[1];
    const int*  mask = (const int*)d_in[2];
    const void* WQ   = d_in[3];
    const void* WK   = d_in[4];
    const void* WV   = d_in[5];
    const void* WO   = d_in[6];

    na_fused<<<dim3(1024), dim3(256), 0, stream>>>(hX, hE, mask, WQ, WK, WV, WO, d_out);
}

// Round 13
// 396.975 us; speedup vs baseline: 1.2459x; 1.0013x over previous
//
#include <hip/hip_runtime.h>
#include <hip/hip_bf16.h>
#include <stdint.h>

// NeighborAttention, MI355X gfx950 — round 13: r10 base + the two SAFE
// DS-reduction changes (head=w softmax, ballot mask bitmasks). The
// v_permlane32_swap_b32 experiment (r11/r12) is abandoned: both polarity
// models of the asm failed correctness; xor-32 exchanges revert to the
// proven __shfl_xor(x,32). DS-pipe ops/wave-node: 49 -> ~27.
//  1) head=w softmax: scores B-frag from sT row (i*4+w) -> every lane holds
//     head w's attn directly; the 9 PV redistribution shuffles are deleted.
//  2) per-node 32-bit mask bitmasks (prologue ballots) -> 1 broadcast ds_read
//     + bit tests instead of 8 ds_read_b32 per wave-node.
// B=4,N=4096,K=32,C=128,H=4,d=32. 16 nodes/block, 256 thr, grid 1024.
// Node-granular double-buffer, 1 non-draining barrier per node (r10).
// LDS 49.5 KB -> 3 blocks/CU.

typedef __attribute__((ext_vector_type(8))) short short8;   // 8 bf16 = 16 B
typedef __attribute__((ext_vector_type(4))) float f32x4;

#define NPB   16
#define CDIM  128
#define KN    32
#define ESTR  136   // LDS row stride (bf16 units)
#define CATS  392   // sCat row stride (bf16 units)
#define NEGI  -3.0e38f

__device__ __forceinline__ float bf2f(short s) {
    union { unsigned int u; float f; } v;
    v.u = ((unsigned int)(unsigned short)s) << 16;
    return v.f;
}
__device__ __forceinline__ short f2bf(float f) {   // RNE scalar
    union { float ff; unsigned int u; } v; v.ff = f;
    unsigned int u = v.u;
    u += 0x7FFFu + ((u >> 16) & 1u);
    return (short)(u >> 16);
}

// 8 x fp32 -> 8 x bf16 via packed cvt (v_cvt_pk_bf16_f32), RNE
__device__ __forceinline__ short8 cvt8(const f32x4& a, const f32x4& b) {
    union { __hip_bfloat162 h; unsigned int u; } c0, c1, c2, c3;
    c0.h = __float22bfloat162_rn(float2{a[0], a[1]});
    c1.h = __float22bfloat162_rn(float2{a[2], a[3]});
    c2.h = __float22bfloat162_rn(float2{b[0], b[1]});
    c3.h = __float22bfloat162_rn(float2{b[2], b[3]});
    short8 r;
    r[0] = (short)(c0.u & 0xffff); r[1] = (short)(c0.u >> 16);
    r[2] = (short)(c1.u & 0xffff); r[3] = (short)(c1.u >> 16);
    r[4] = (short)(c2.u & 0xffff); r[5] = (short)(c2.u >> 16);
    r[6] = (short)(c3.u & 0xffff); r[7] = (short)(c3.u >> 16);
    return r;
}

template<bool FP32>
__device__ __forceinline__ short8 load8bf(const void* p, size_t idx) {
    if constexpr (FP32) {
        const float* fp = (const float*)p + idx;
        f32x4 a = *(const f32x4*)fp;
        f32x4 b = *(const f32x4*)(fp + 4);
        return cvt8(a, b);
    } else {
        return *(const short8*)((const short*)p + idx);
    }
}

template<bool FP32>
__device__ __forceinline__ short loadbf1(const void* p, size_t idx) {
    if constexpr (FP32) return f2bf(((const float*)p)[idx]);
    else return ((const short*)p)[idx];
}

// in-kernel dtype detect: fp32 low half-words decode to wild/NaN bf16s
__device__ __forceinline__ bool detect_fp32(const short* wp) {
    const int lane = threadIdx.x & 63;
    int cnt = 0;
    #pragma unroll
    for (int i = 0; i < 8; ++i) {
        const float v = bf2f(wp[lane + i * 64]);
        if (!(fabsf(v) < 8.0f)) cnt++;
    }
    #pragma unroll
    for (int d = 1; d < 64; d <<= 1) cnt += __shfl_xor(cnt, d);
    return cnt > 16;
}

struct alignas(16) Smem {
    short sEb[2][32 * ESTR];   // 17408 B  double-buffered 32-row node tiles
    short sT[64 * ESTR];       // 17408 B  t = (q·Wk)*scale (bf16), row=(n,h)
    union {
        short sQ[16 * ESTR];   //  4352 B  q rows (prologue only)
        short sCat[16 * CATS]; // 12544 B  [mean|sum|max] (main loop + epilogue)
    } u;
    int      sMask[NPB * KN];  //  2048 B  raw mask (prologue / ballot source)
    unsigned sMaskBits[NPB];   //    64 B  bit k = (mask[node][k] > 0)
};                             // 49472 B -> 3 blocks/CU

// issue loads for one 32x128 node tile (16 KB fp32 / 8 KB bf16), 64 B/thread
template<bool FP32>
__device__ __forceinline__ void issueN(const void* hE, size_t base, int tid,
                                       f32x4 (&pF)[2][2], short8 (&pB)[2]) {
    if constexpr (FP32) {
        #pragma unroll
        for (int it = 0; it < 2; ++it) {
            const float* p = (const float*)hE + base + (size_t)(it * 256 + tid) * 8;
            pF[it][0] = *(const f32x4*)p;
            pF[it][1] = *(const f32x4*)(p + 4);
        }
    } else {
        #pragma unroll
        for (int it = 0; it < 2; ++it)
            pB[it] = *(const short8*)((const short*)hE + base + (size_t)(it * 256 + tid) * 8);
    }
    __builtin_amdgcn_sched_barrier(0);   // pin issue position (r4-proven)
}

template<bool FP32>
__device__ __forceinline__ void writeN(short* dst, int tid,
                                       const f32x4 (&pF)[2][2], const short8 (&pB)[2]) {
    #pragma unroll
    for (int it = 0; it < 2; ++it) {
        const int chunk = it * 256 + tid, row = chunk >> 4, cc = chunk & 15;
        short8 v;
        if constexpr (FP32) v = cvt8(pF[it][0], pF[it][1]);
        else                v = pB[it];
        *(short8*)&dst[row * ESTR + cc * 8] = v;
    }
}

template<bool FP32>
__device__ __forceinline__ void na_body(Smem& sm,
    const void* __restrict__ hX, const void* __restrict__ hE,
    const int* __restrict__ mask, const void* __restrict__ WQ,
    const void* __restrict__ WK, const void* __restrict__ WV,
    const void* __restrict__ WO, void* __restrict__ out)
{
    const int tid  = threadIdx.x;
    const int lane = tid & 63;
    const int w    = tid >> 6;      // wave 0..3 == head owner
    const int quad = lane >> 4;
    const int l15  = lane & 15;
    const int nb   = blockIdx.x * NPB;
    const size_t ebase = (size_t)nb * (KN * CDIM);

    // ---- issue E(node 0) prefetch first ----
    f32x4 pF[2][2]; short8 pB[2];
    issueN<FP32>(hE, ebase, tid, pF, pB);

    // ---- stage mask (coalesced, 2 ints/thread) ----
    *(int2*)&sm.sMask[tid * 2] = *(const int2*)&mask[(size_t)nb * KN + tid * 2];

    // ---- X A-frags + WQ B-frags; q = X @ WQ^T -> u.sQ ----
    short8 ax[4];
    #pragma unroll
    for (int kk = 0; kk < 4; ++kk)
        ax[kk] = load8bf<FP32>(hX, (size_t)(nb + l15) * CDIM + kk * 32 + quad * 8);
    short8 bq[2][4];
    #pragma unroll
    for (int t2 = 0; t2 < 2; ++t2)
        #pragma unroll
        for (int kk = 0; kk < 4; ++kk)
            bq[t2][kk] = load8bf<FP32>(WQ, (size_t)(w * 32 + t2 * 16 + l15) * CDIM + kk * 32 + quad * 8);
    {
        f32x4 o0 = {0.f,0.f,0.f,0.f}, o1 = {0.f,0.f,0.f,0.f};
        #pragma unroll
        for (int kk = 0; kk < 4; ++kk) {
            o0 = __builtin_amdgcn_mfma_f32_16x16x32_bf16(ax[kk], bq[0][kk], o0, 0, 0, 0);
            o1 = __builtin_amdgcn_mfma_f32_16x16x32_bf16(ax[kk], bq[1][kk], o1, 0, 0, 0);
        }
        #pragma unroll
        for (int r = 0; r < 4; ++r) {
            const int n = quad * 4 + r;
            sm.u.sQ[n * ESTR + w * 32 + l15]      = f2bf(o0[r]);
            sm.u.sQ[n * ESTR + w * 32 + 16 + l15] = f2bf(o1[r]);
        }
    }
    __syncthreads();   // B1: sQ + sMask ready

    // ---- per-node mask bitmasks: wave w ballots nodes 4w..4w+3 ----
    #pragma unroll
    for (int t = 0; t < 4; ++t) {
        const int n = w * 4 + t;
        const bool bit = (lane < 32) && (sm.sMask[n * KN + (lane & 31)] > 0);
        const unsigned long long bal = __ballot(bit);
        if (lane == 0) sm.sMaskBits[n] = (unsigned)bal;
    }

    // ---- WK B-frags (gather) ; t = (q·WK)*scale -> sT (row=(n,h)) ----
    short8 bk[2][4];
    #pragma unroll
    for (int t2 = 0; t2 < 2; ++t2)
        #pragma unroll
        for (int kk = 0; kk < 4; ++kk) {
            const int j = w * 32 + t2 * 16 + l15;
            short8 b;
            #pragma unroll
            for (int jj = 0; jj < 8; ++jj)
                b[jj] = loadbf1<FP32>(WK, (size_t)(kk * 32 + quad * 8 + jj) * CDIM + j);
            bk[t2][kk] = b;
        }
    {
        const float scale = 0.17677669529663687f;   // 1/sqrt(32)
        const short8 zz = {0,0,0,0,0,0,0,0};
        #pragma unroll
        for (int m = 0; m < 4; ++m) {
            const int n_g = m * 4 + (l15 >> 2), h_ = l15 & 3;
            const short8 qv = *(const short8*)&sm.u.sQ[n_g * ESTR + h_ * 32 + quad * 8];
            f32x4 c0 = {0.f,0.f,0.f,0.f}, c1 = {0.f,0.f,0.f,0.f};
            #pragma unroll
            for (int kk = 0; kk < 4; ++kk) {
                const short8 af = (kk == h_) ? qv : zz;
                c0 = __builtin_amdgcn_mfma_f32_16x16x32_bf16(af, bk[0][kk], c0, 0, 0, 0);
                c1 = __builtin_amdgcn_mfma_f32_16x16x32_bf16(af, bk[1][kk], c1, 0, 0, 0);
            }
            #pragma unroll
            for (int r = 0; r < 4; ++r) {
                const int row = m * 16 + quad * 4 + r;        // (n,h) row
                sm.sT[row * ESTR + w * 32 + l15]      = f2bf(c0[r] * scale);
                sm.sT[row * ESTR + w * 32 + 16 + l15] = f2bf(c1[r] * scale);
            }
        }
    }

    // ---- WV B-frags (block lifetime, wave w owns channel cols 32w..+31) ----
    short8 bv[2][4];
    #pragma unroll
    for (int ct2 = 0; ct2 < 2; ++ct2)
        #pragma unroll
        for (int kk = 0; kk < 4; ++kk)
            bv[ct2][kk] = load8bf<FP32>(WV, (size_t)((2 * w + ct2) * 16 + l15) * CDIM + kk * 32 + quad * 8);

    // ---- stage node 0, issue node 1 ----
    writeN<FP32>(sm.sEb[0], tid, pF, pB);
    issueN<FP32>(hE, ebase + 1 * (KN * CDIM), tid, pF, pB);
    __syncthreads();   // B2: sT + sEb[0] + sMaskBits ready; pf = E(1) in flight

    // ================= node loop: 1 NON-DRAINING barrier per node ============
    #pragma unroll 1
    for (int i = 0; i < NPB; ++i) {
        const short* bufp = sm.sEb[i & 1];

        // ---- frags: A = node rows; B = t row (i*4 + w) -> HEAD w broadcast ----
        short8 a0[4], a1[4], bs[4];
        #pragma unroll
        for (int kk = 0; kk < 4; ++kk) {
            bs[kk] = *(const short8*)&sm.sT[(i * 4 + w) * ESTR + kk * 32 + quad * 8];
            a0[kk] = *(const short8*)&bufp[l15 * ESTR + kk * 32 + quad * 8];
            a1[kk] = *(const short8*)&bufp[(16 + l15) * ESTR + kk * 32 + quad * 8];
        }

        // ---- scores for head w: every col identical; row -> k ----
        f32x4 s0 = {0.f,0.f,0.f,0.f}, s1 = {0.f,0.f,0.f,0.f};
        #pragma unroll
        for (int kk = 0; kk < 4; ++kk) {
            s0 = __builtin_amdgcn_mfma_f32_16x16x32_bf16(a0[kk], bs[kk], s0, 0, 0, 0);
            s1 = __builtin_amdgcn_mfma_f32_16x16x32_bf16(a1[kk], bs[kk], s1, 0, 0, 0);
        }

        // ---- masked softmax (head w) fully in-register; bitmask masks ----
        float x[8], ainv;
        {
            const unsigned mb = sm.sMaskBits[i];   // broadcast ds_read_b32
            float m = NEGI;
            #pragma unroll
            for (int j = 0; j < 4; ++j) {
                x[j]     = s0[j];
                x[4 + j] = s1[j];
                m = fmaxf(m, ((mb >> (quad * 4 + j)) & 1u)      ? s0[j] : NEGI);
                m = fmaxf(m, ((mb >> (16 + quad * 4 + j)) & 1u) ? s1[j] : NEGI);
            }
            m = fmaxf(m, __shfl_xor(m, 16));
            m = fmaxf(m, __shfl_xor(m, 32));
            float dsum = 0.f;
            #pragma unroll
            for (int j = 0; j < 4; ++j) {
                const float e0 = __expf(fminf(x[j] - m, 0.f))
                                 * (((mb >> (quad * 4 + j)) & 1u) ? 1.f : 0.f);
                const float e1 = __expf(fminf(x[4 + j] - m, 0.f))
                                 * (((mb >> (16 + quad * 4 + j)) & 1u) ? 1.f : 0.f);
                x[j] = e0; x[4 + j] = e1;
                dsum += e0 + e1;
            }
            dsum += __shfl_xor(dsum, 16);
            dsum += __shfl_xor(dsum, 32);
            const float inv = (dsum > 0.f) ? (1.f / dsum) : 0.f;
            #pragma unroll
            for (int j = 0; j < 8; ++j) x[j] *= inv;
            ainv = 1.0f / (((dsum > 0.f) ? 1.0f : 0.0f) + 1e-8f);
        }

        // ---- stage next node into the other buffer; issue node i+2 ----
        if (i < NPB - 1) {
            writeN<FP32>(sm.sEb[(i + 1) & 1], tid, pF, pB);   // pf = E(i+1)
            if (i < NPB - 2)
                issueN<FP32>(hE, ebase + (size_t)(i + 2) * (KN * CDIM), tid, pF, pB);
        }

        // ---- PV + aggregation: lane already holds head-w attn (no shuffles) --
        #pragma unroll
        for (int ct2 = 0; ct2 < 2; ++ct2) {
            f32x4 av0 = {0.f,0.f,0.f,0.f}, av1 = {0.f,0.f,0.f,0.f};
            #pragma unroll
            for (int kk = 0; kk < 4; ++kk) {
                av0 = __builtin_amdgcn_mfma_f32_16x16x32_bf16(a0[kk], bv[ct2][kk], av0, 0, 0, 0);
                av1 = __builtin_amdgcn_mfma_f32_16x16x32_bf16(a1[kk], bv[ct2][kk], av1, 0, 0, 0);
            }
            float sum = 0.f, mx = NEGI;
            #pragma unroll
            for (int r = 0; r < 4; ++r) {
                const float p0 = x[r]     * av0[r];
                const float p1 = x[4 + r] * av1[r];
                sum += p0 + p1;
                mx = fmaxf(mx, fmaxf(p0, p1));
            }
            sum += __shfl_xor(sum, 16);
            sum += __shfl_xor(sum, 32);
            mx = fmaxf(mx, __shfl_xor(mx, 16));
            mx = fmaxf(mx, __shfl_xor(mx, 32));
            if (quad == 0) {
                const int c = (2 * w + ct2) * 16 + l15;
                sm.u.sCat[i * CATS + c]       = f2bf(sum * ainv);  // mean
                sm.u.sCat[i * CATS + 128 + c] = f2bf(sum);         // sum
                sm.u.sCat[i * CATS + 256 + c] = f2bf(mx);          // max
            }
        }

        // ---- NON-DRAINING barrier (r10): lgkmcnt only, no vmcnt drain ----
        asm volatile("s_waitcnt lgkmcnt(0)" ::: "memory");
        __builtin_amdgcn_s_barrier();
        __builtin_amdgcn_sched_barrier(0);
    }
    __syncthreads();   // full drain before epilogue reads sCat

    // ---- P7: out = cat @ WO^T via MFMA (M=16, K=384, wave owns 32 cols) ----
    {
        f32x4 o0 = {0.f,0.f,0.f,0.f}, o1 = {0.f,0.f,0.f,0.f};
        #pragma unroll
        for (int kk = 0; kk < 12; ++kk) {
            const short8 a  = *(const short8*)&sm.u.sCat[l15 * CATS + kk * 32 + quad * 8];
            const short8 b0 = load8bf<FP32>(WO, (size_t)(w * 32 + l15) * 384 + kk * 32 + quad * 8);
            const short8 b1 = load8bf<FP32>(WO, (size_t)(w * 32 + 16 + l15) * 384 + kk * 32 + quad * 8);
            o0 = __builtin_amdgcn_mfma_f32_16x16x32_bf16(a, b0, o0, 0, 0, 0);
            o1 = __builtin_amdgcn_mfma_f32_16x16x32_bf16(a, b1, o1, 0, 0, 0);
        }
        #pragma unroll
        for (int r = 0; r < 4; ++r) {
            const int node = quad * 4 + r;
            const size_t base = (size_t)(nb + node) * CDIM + w * 32;
            if constexpr (FP32) {
                ((float*)out)[base + l15]      = o0[r];
                ((float*)out)[base + 16 + l15] = o1[r];
            } else {
                ((short*)out)[base + l15]      = f2bf(o0[r]);
                ((short*)out)[base + 16 + l15] = f2bf(o1[r]);
            }
        }
    }
}

__global__ __launch_bounds__(256, 3)
void na_fused(const void* __restrict__ hX, const void* __restrict__ hE,
              const int* __restrict__ mask, const void* __restrict__ WQ,
              const void* __restrict__ WK, const void* __restrict__ WV,
              const void* __restrict__ WO, void* __restrict__ out)
{
    __shared__ Smem sm;
    if (detect_fp32((const short*)WQ)) na_body<true >(sm, hX, hE, mask, WQ, WK, WV, WO, out);
    else                               na_body<false>(sm, hX, hE, mask, WQ, WK, WV, WO, out);
}

extern "C" void kernel_launch(void* const* d_in, const int* in_sizes, int n_in,
                              void* d_out, int out_size, void* d_ws, size_t ws_size,
                              hipStream_t stream) {
    (void)in_sizes; (void)n_in; (void)ws_size; (void)out_size; (void)d_ws;
    const void* hX   = d_in[0];
    const void* hE   = d_in[1];
    const int*  mask = (const int*)d_in[2];
    const void* WQ   = d_in[3];
    const void* WK   = d_in[4];
    const void* WV   = d_in[5];
    const void* WO   = d_in[6];

    na_fused<<<dim3(1024), dim3(256), 0, stream>>>(hX, hE, mask, WQ, WK, WV, WO, d_out);
}